// Round 9
// baseline (344.646 us; speedup 1.0000x reference)
//
#include <hip/hip_runtime.h>
#include <hip/hip_bf16.h>

typedef __bf16 bf16;
typedef __bf16 bf16x8 __attribute__((ext_vector_type(8)));
typedef __bf16 bf16x4 __attribute__((ext_vector_type(4)));
typedef float f32x4 __attribute__((ext_vector_type(4)));

#define B_    2
#define S_    2048
#define HD    2048
#define NH    16
#define DQK   192
#define DV    128
#define QR    1536
#define KVR   512
#define NTOK  4096
#define NKVB  4096   /* N_HEADS*(D_NOPE+D_V) */
#define NQB   3072   /* N_HEADS*D_QK */
#define NQKVA 2176   /* QR + 640 (padded kv_a) */

#define EXP2F(x) __builtin_amdgcn_exp2f(x)

static __device__ __forceinline__ void gload16(const void* g, void* l) {
  __builtin_amdgcn_global_load_lds(
      (const __attribute__((address_space(1))) void*)g,
      (__attribute__((address_space(3))) void*)l, 16, 0, 0);
}

// ---------------- f32 -> bf16 convert ----------------
__global__ __launch_bounds__(256) void cvt_bf16(const float* __restrict__ in,
                                                bf16* __restrict__ out, long n) {
  long i = ((long)blockIdx.x * 256 + threadIdx.x) * 4;
  if (i + 3 < n) {
    float4 v = *(const float4*)(in + i);
    bf16x4 o = {(bf16)v.x, (bf16)v.y, (bf16)v.z, (bf16)v.w};
    *(bf16x4*)(out + i) = o;
  }
}

// ---------------- transpose f32 [R][C] -> bf16 [Np][R], zero-pad rows >= C ----
__global__ __launch_bounds__(256) void transpose_cvt(const float* __restrict__ in,
                                                     bf16* __restrict__ out,
                                                     int R, int C, int Np) {
  __shared__ float tile[32][33];
  int c0 = blockIdx.x * 32;
  int r0 = blockIdx.y * 32;
  int tx = threadIdx.x & 31, ty = threadIdx.x >> 5;
#pragma unroll
  for (int i = 0; i < 4; ++i) {
    int r = r0 + ty + i * 8, c = c0 + tx;
    tile[ty + i * 8][tx] = (c < C) ? in[(long)r * C + c] : 0.f;
  }
  __syncthreads();
#pragma unroll
  for (int i = 0; i < 4; ++i) {
    int oc = c0 + ty + i * 8;
    if (oc < Np) out[(long)oc * R + r0 + tx] = (bf16)tile[tx][ty + i * 8];
  }
}

// ============ gemm2p core: 256(M)x128(N) tile, BK=64, 8 waves, 3-buf LDS ======
// Deep pipeline: stage tile kt+2 during kt; vmcnt(6) at tile entry (counted,
// never 0 in steady state); 2 phases/tile, 16-MFMA clusters with setprio.
// Wave grid 4M x 2N; per-wave 64x64 output (acc[4][4] of 16x16 frags).
#define G2P_CORE(A, Bt, K)                                                     \
  __shared__ bf16 La[3][256 * 64];                                             \
  __shared__ bf16 Lb[3][128 * 64];                                             \
  const int t = threadIdx.x;                                                   \
  const int w = t >> 6, l = t & 63;                                            \
  const int lr = l & 15, lg = l >> 4;                                          \
  const int wm = w >> 1, wn = w & 1;                                           \
  const int m0 = blockIdx.y * 256, n0 = blockIdx.x * 128;                      \
  const int NT = (K) >> 6;                                                     \
  const int tr = t >> 3, sc = t & 7;                                           \
  f32x4 acc[4][4] = {};                                                        \
  /* staging helpers: round r covers rows r*64..r*64+63, 8 chunks each */      \
  auto stA = [&](int kt, int r) {                                              \
    int row = r * 64 + tr;                                                     \
    int c = sc ^ (row & 7);                                                    \
    gload16((A) + (long)(m0 + row) * (K) + kt * 64 + c * 8,                    \
            &La[kt % 3][(r * 512 + w * 64) * 8]);                              \
  };                                                                           \
  auto stB = [&](int kt, int r) {                                              \
    int row = r * 64 + tr;                                                     \
    int c = sc ^ (row & 7);                                                    \
    gload16((Bt) + (long)(n0 + row) * (K) + kt * 64 + c * 8,                   \
            &Lb[kt % 3][(r * 512 + w * 64) * 8]);                              \
  };                                                                           \
  /* prologue: stage tiles 0 and 1 (6 loads each) */                           \
  stA(0, 0); stA(0, 1); stA(0, 2); stA(0, 3); stB(0, 0); stB(0, 1);            \
  stA(1, 0); stA(1, 1); stA(1, 2); stA(1, 3); stB(1, 0); stB(1, 1);            \
  for (int kt = 0; kt < NT; ++kt) {                                            \
    const bf16* Ab = &La[kt % 3][0];                                           \
    const bf16* Bb = &Lb[kt % 3][0];                                           \
    bool more = (kt + 2) < NT;                                                 \
    /* ---- phase 0: vmcnt -> barrier -> reads -> stage -> MFMA(ni 0,1) ---- */\
    if (kt == NT - 1) { asm volatile("s_waitcnt vmcnt(0)" ::: "memory"); }     \
    else              { asm volatile("s_waitcnt vmcnt(6)" ::: "memory"); }     \
    __builtin_amdgcn_s_barrier();                                              \
    bf16x8 af[4][2], bf0[2][2];                                                \
    _Pragma("unroll")                                                          \
    for (int mi = 0; mi < 4; ++mi) {                                           \
      int row = wm * 64 + mi * 16 + lr;                                        \
      _Pragma("unroll")                                                        \
      for (int kh = 0; kh < 2; ++kh)                                           \
        af[mi][kh] = *(const bf16x8*)(Ab + row * 64 + (((kh * 4 + lg) ^ (row & 7)) << 3)); \
    }                                                                          \
    _Pragma("unroll")                                                          \
    for (int ni = 0; ni < 2; ++ni) {                                           \
      int row = wn * 64 + ni * 16 + lr;                                        \
      _Pragma("unroll")                                                        \
      for (int kh = 0; kh < 2; ++kh)                                           \
        bf0[ni][kh] = *(const bf16x8*)(Bb + row * 64 + (((kh * 4 + lg) ^ (row & 7)) << 3)); \
    }                                                                          \
    if (more) { stA(kt + 2, 0); stA(kt + 2, 1); stA(kt + 2, 2); }              \
    asm volatile("s_waitcnt lgkmcnt(0)" ::: "memory");                         \
    __builtin_amdgcn_sched_barrier(0);                                         \
    __builtin_amdgcn_s_setprio(1);                                             \
    _Pragma("unroll")                                                          \
    for (int mi = 0; mi < 4; ++mi)                                             \
      _Pragma("unroll")                                                        \
      for (int ni = 0; ni < 2; ++ni)                                           \
        _Pragma("unroll")                                                      \
        for (int kh = 0; kh < 2; ++kh)                                         \
          acc[mi][ni] = __builtin_amdgcn_mfma_f32_16x16x32_bf16(af[mi][kh], bf0[ni][kh], acc[mi][ni], 0, 0, 0); \
    __builtin_amdgcn_s_setprio(0);                                             \
    __builtin_amdgcn_s_barrier();                                              \
    /* ---- phase 1: reads -> stage -> barrier -> MFMA(ni 2,3) ---- */         \
    bf16x8 bf1[2][2];                                                          \
    _Pragma("unroll")                                                          \
    for (int ni = 0; ni < 2; ++ni) {                                           \
      int row = wn * 64 + (ni + 2) * 16 + lr;                                  \
      _Pragma("unroll")                                                        \
      for (int kh = 0; kh < 2; ++kh)                                           \
        bf1[ni][kh] = *(const bf16x8*)(Bb + row * 64 + (((kh * 4 + lg) ^ (row & 7)) << 3)); \
    }                                                                          \
    if (more) { stA(kt + 2, 3); stB(kt + 2, 0); stB(kt + 2, 1); }              \
    __builtin_amdgcn_s_barrier();                                              \
    asm volatile("s_waitcnt lgkmcnt(0)" ::: "memory");                         \
    __builtin_amdgcn_sched_barrier(0);                                         \
    __builtin_amdgcn_s_setprio(1);                                             \
    _Pragma("unroll")                                                          \
    for (int mi = 0; mi < 4; ++mi)                                             \
      _Pragma("unroll")                                                        \
      for (int ni = 0; ni < 2; ++ni)                                           \
        _Pragma("unroll")                                                      \
        for (int kh = 0; kh < 2; ++kh)                                         \
          acc[mi][ni + 2] = __builtin_amdgcn_mfma_f32_16x16x32_bf16(af[mi][kh], bf1[ni][kh], acc[mi][ni + 2], 0, 0, 0); \
    __builtin_amdgcn_s_setprio(0);                                             \
    __builtin_amdgcn_s_barrier();                                              \
  }

// ---------------- generic: C[M][N] = A @ Bt^T ---------------------------------
template <typename CT>
__global__ __launch_bounds__(512) void gemm2p(const bf16* __restrict__ A,
                                              const bf16* __restrict__ Bt,
                                              CT* __restrict__ C,
                                              int M, int N, int K) {
  G2P_CORE(A, Bt, K)
#pragma unroll
  for (int mi = 0; mi < 4; ++mi)
#pragma unroll
    for (int ni = 0; ni < 4; ++ni)
#pragma unroll
      for (int vv = 0; vv < 4; ++vv) {
        int row = m0 + wm * 64 + mi * 16 + lg * 4 + vv;
        int col = n0 + wn * 64 + ni * 16 + lr;
        C[(long)row * N + col] = (CT)acc[mi][ni][vv];
      }
}

// ---------------- fused q_f: epilogue RoPE + SCALE*LOG2E -> q_bhsd ------------
__global__ __launch_bounds__(512) void gemm2p_qf(const bf16* __restrict__ A,
                                                 const bf16* __restrict__ Bt,
                                                 const int* __restrict__ pos,
                                                 const float* __restrict__ cosT,
                                                 const float* __restrict__ sinT,
                                                 bf16* __restrict__ q_bhsd) {
  const float SCALE = 0.07216878364870323f * 1.4426950408889634f;
  G2P_CORE(A, Bt, QR)
  int c0 = n0 + wn * 64;
  int h = c0 / 192;
  int part = c0 - h * 192;            // 0, 64, or 128 (wave-uniform)
#pragma unroll
  for (int mi = 0; mi < 4; ++mi)
#pragma unroll
    for (int vv = 0; vv < 4; ++vv) {
      int row = m0 + wm * 64 + mi * 16 + lg * 4 + vv;
      int b = row >> 11, s = row & (S_ - 1);
      long base = ((long)(b * NH + h) * S_ + s) * DQK;
      if (part < 128) {
#pragma unroll
        for (int ni = 0; ni < 4; ++ni)
          q_bhsd[base + part + ni * 16 + lr] = (bf16)(acc[mi][ni][vv] * SCALE);
      } else {
        int p = pos[s] & (S_ - 1);
        float c_lo = cosT[p * 32 + lr],      s_lo = sinT[p * 32 + lr];
        float c_hi = cosT[p * 32 + 16 + lr], s_hi = sinT[p * 32 + 16 + lr];
        float o0 = acc[mi][0][vv] * c_lo - acc[mi][2][vv] * s_lo;
        float o1 = acc[mi][1][vv] * c_hi - acc[mi][3][vv] * s_hi;
        float o2 = acc[mi][0][vv] * s_lo + acc[mi][2][vv] * c_lo;
        float o3 = acc[mi][1][vv] * s_hi + acc[mi][3][vv] * c_hi;
        q_bhsd[base + 128 + lr] = (bf16)(o0 * SCALE);
        q_bhsd[base + 144 + lr] = (bf16)(o1 * SCALE);
        q_bhsd[base + 160 + lr] = (bf16)(o2 * SCALE);
        q_bhsd[base + 176 + lr] = (bf16)(o3 * SCALE);
      }
    }
}

// ---------------- fused kv_b: k-part -> k_bhsd, v-part -> v_rows --------------
__global__ __launch_bounds__(512) void gemm2p_kvb(const bf16* __restrict__ A,
                                                  const bf16* __restrict__ Bt,
                                                  bf16* __restrict__ k_bhsd,
                                                  bf16* __restrict__ v_rows) {
  G2P_CORE(A, Bt, KVR)
  int c0 = n0 + wn * 64;
  int h = c0 >> 8;
  int dbase = c0 & 64;
  bool vpart = (c0 >> 7) & 1;
#pragma unroll
  for (int mi = 0; mi < 4; ++mi)
#pragma unroll
    for (int vv = 0; vv < 4; ++vv) {
      int row = m0 + wm * 64 + mi * 16 + lg * 4 + vv;
      int b = row >> 11, s = row & (S_ - 1);
      if (!vpart) {
        long base = ((long)(b * NH + h) * S_ + s) * DQK + dbase;
#pragma unroll
        for (int ni = 0; ni < 4; ++ni)
          k_bhsd[base + ni * 16 + lr] = (bf16)acc[mi][ni][vv];
      } else {
        long base = (long)row * 2048 + h * 128 + dbase;
#pragma unroll
        for (int ni = 0; ni < 4; ++ni)
          v_rows[base + ni * 16 + lr] = (bf16)acc[mi][ni][vv];
      }
    }
}

// ---------------- merged norm+prep: waves 0-2 q-RMSNorm, wave 3 kv+rope -------
__global__ __launch_bounds__(256) void norm_prep(const bf16* __restrict__ xa,   // [NTOK][2176]
                                                 const float* __restrict__ g_qa,
                                                 const float* __restrict__ g_kva,
                                                 const int* __restrict__ pos,
                                                 const float* __restrict__ cosT,
                                                 const float* __restrict__ sinT,
                                                 bf16* __restrict__ q_n,       // [NTOK][1536]
                                                 bf16* __restrict__ kv_l,      // [NTOK][512]
                                                 bf16* __restrict__ k_bhsd) {  // [B][H][S][192]
  int row = blockIdx.x;
  int t = threadIdx.x;
  int b = row >> 11, s = row & (S_ - 1);
  const bf16* xr = xa + (long)row * NQKVA;
  __shared__ float red[3];
  __shared__ bf16 rope_s[64];
  float vf[8];
  if (t < 192) {
    bf16x8 vv = *(const bf16x8*)(xr + t * 8);
    float ss = 0.f;
#pragma unroll
    for (int e = 0; e < 8; ++e) { vf[e] = (float)vv[e]; ss += vf[e] * vf[e]; }
#pragma unroll
    for (int m = 1; m < 64; m <<= 1) ss += __shfl_xor(ss, m);
    if ((t & 63) == 0) red[t >> 6] = ss;
  } else {
    int tt = t - 192;
    const bf16* xl = xr + QR;
    bf16x8 vv = *(const bf16x8*)(xl + tt * 8);
    float ss = 0.f;
#pragma unroll
    for (int e = 0; e < 8; ++e) { vf[e] = (float)vv[e]; ss += vf[e] * vf[e]; }
#pragma unroll
    for (int m = 1; m < 64; m <<= 1) ss += __shfl_xor(ss, m);
    float rs = rsqrtf(ss / KVR + 1e-5f);
    bf16x8 o;
#pragma unroll
    for (int e = 0; e < 8; ++e) o[e] = (bf16)(vf[e] * rs * g_kva[tt * 8 + e]);
    *(bf16x8*)(kv_l + (long)row * KVR + tt * 8) = o;
    if (tt < 32) {
      int p = pos[s] & (S_ - 1);
      float c = cosT[p * 32 + tt], sn = sinT[p * 32 + tt];
      float x0 = (float)xl[512 + tt], x1 = (float)xl[544 + tt];
      rope_s[tt] = (bf16)(x0 * c - x1 * sn);
      rope_s[32 + tt] = (bf16)(x0 * sn + x1 * c);
    }
  }
  __syncthreads();
  if (t < 192) {
    float ss = red[0] + red[1] + red[2];
    float rs = rsqrtf(ss / QR + 1e-5f);
    bf16x8 o;
#pragma unroll
    for (int e = 0; e < 8; ++e) o[e] = (bf16)(vf[e] * rs * g_qa[t * 8 + e]);
    *(bf16x8*)(q_n + (long)row * QR + t * 8) = o;
  } else {
    int tt = t - 192;
    bf16x8 rv = *(const bf16x8*)&rope_s[(tt & 7) * 8];
    long base0 = ((long)(b * NH + (tt >> 3)) * S_ + s) * DQK + 128 + (tt & 7) * 8;
    long base1 = ((long)(b * NH + 8 + (tt >> 3)) * S_ + s) * DQK + 128 + (tt & 7) * 8;
    *(bf16x8*)(k_bhsd + base0) = rv;
    *(bf16x8*)(k_bhsd + base1) = rv;
  }
}

// ---------------- V transpose: v_rows [NTOK][2048] -> v_t [BH][128][S] --------
__global__ __launch_bounds__(256) void v_trans(const bf16* __restrict__ v_rows,
                                               bf16* __restrict__ v_t) {
  __shared__ bf16 tile[32][33];
  int st = blockIdx.x, dt = blockIdx.y, bh = blockIdx.z;
  int b = bh >> 4, h = bh & 15;
  int tx = threadIdx.x & 31, ty = threadIdx.x >> 5;
#pragma unroll
  for (int i = 0; i < 4; ++i) {
    int s = st * 32 + ty + i * 8, d = dt * 32 + tx;
    tile[ty + i * 8][tx] = v_rows[((long)(b * S_ + s)) * 2048 + h * 128 + d];
  }
  __syncthreads();
#pragma unroll
  for (int i = 0; i < 4; ++i) {
    int d = dt * 32 + ty + i * 8, s = st * 32 + tx;
    v_t[((long)bh * DV + d) * S_ + s] = tile[tx][ty + i * 8];
  }
}

// ---------------- flash v2b: ones-row PV computes l; exp2 softmax; setprio ----
#define QBLK 64
#define KVB  64
#define DVP  144
__global__ __launch_bounds__(256) void flash2(const bf16* __restrict__ q_bhsd,
                                              const bf16* __restrict__ k_bhsd,
                                              const bf16* __restrict__ v_t,
                                              bf16* __restrict__ att) {  // [NTOK][2048]
  __shared__ bf16 Ks[KVB * DQK];      // 24 KB, swizzled 16B chunks
  __shared__ bf16 Vs[DVP * KVB];      // 18 KB, rows 0-127 staged, 128-143 const
  __shared__ bf16 Ps[4][16 * 72];     // 9 KB, per-wave P, padded to 72
  int bid = blockIdx.x;
  int bh = bid & 31;                  // head-of-batch: fixes XCD = bh%8
  int qt = 31 - (bid >> 5);           // heaviest (most k-tiles) first
  int b = bh >> 4, h = bh & 15;
  int q0 = qt * QBLK;
  int t = threadIdx.x;
  int w = t >> 6, l = t & 63;
  int lr = l & 15, lg = l >> 4;
  int qw = q0 + w * 16;               // this wave's first q row

  const bf16* Qb = q_bhsd + (long)bh * S_ * DQK;
  const bf16* Kb = k_bhsd + (long)bh * S_ * DQK;
  const bf16* Vb = v_t + (long)bh * DV * S_;

  // init ones/zero rows of Vs (persist across tiles; staging never touches them)
  if (t < 128) {
    int rr = 128 + (t >> 3), cc = (t & 7) * 8;
    bf16 val = (bf16)((rr == 128) ? 1.0f : 0.0f);
    bf16x8 vvv = {val, val, val, val, val, val, val, val};
    *(bf16x8*)(Vs + rr * KVB + cc) = vvv;
  }

  bf16x8 qf[6];
#pragma unroll
  for (int t6 = 0; t6 < 6; ++t6)
    qf[t6] = *(const bf16x8*)(Qb + (long)(qw + lr) * DQK + t6 * 32 + lg * 8);

  f32x4 oacc[9] = {};                 // [0..7] output, [8] = l (ones-row)
  float mrow[4] = {-1e30f, -1e30f, -1e30f, -1e30f};
  const int lr7 = lr & 7;

  int nkt = qt + 1;
  for (int kt = 0; kt < nkt; ++kt) {
    int k0 = kt * KVB;
    __syncthreads();
    // stage K: 1536 chunks (6 x 256); slot s holds global chunk (r, c^(r&7))
#pragma unroll
    for (int j = 0; j < 6; ++j) {
      int s = j * 256 + t;
      int r = s / 24, c1 = s - r * 24;
      int c = c1 ^ (r & 7);
      gload16(Kb + (long)(k0 + r) * DQK + c * 8, Ks + (j * 256 + w * 64) * 8);
    }
    // stage V: 1024 chunks (4 x 256), rows 0..127 only
#pragma unroll
    for (int j = 0; j < 4; ++j) {
      int s = j * 256 + t;
      int d = s >> 3, c1 = s & 7;
      int c = c1 ^ (d & 7);
      gload16(Vb + (long)d * S_ + k0 + c * 8, Vs + (j * 256 + w * 64) * 8);
    }
    __syncthreads();
    if (k0 > qw + 15) continue;       // fully masked for this wave

    // ---- QK^T: sacc[n] = scores[q=lg*4+v][k=n*16+lr] (log2-domain) ----
    f32x4 sacc[4] = {};
    __builtin_amdgcn_s_setprio(1);
#pragma unroll
    for (int n = 0; n < 4; ++n) {
      int rk = n * 16 + lr;
#pragma unroll
      for (int t6 = 0; t6 < 6; ++t6) {
        bf16x8 kf = *(const bf16x8*)(Ks + rk * DQK + (((t6 * 4 + lg) ^ lr7) << 3));
        sacc[n] = __builtin_amdgcn_mfma_f32_16x16x32_bf16(qf[t6], kf, sacc[n], 0, 0, 0);
      }
    }
    __builtin_amdgcn_s_setprio(0);
    // ---- causal mask (diagonal tiles only) ----
    if (k0 + KVB - 1 > qw) {
#pragma unroll
      for (int n = 0; n < 4; ++n)
#pragma unroll
        for (int v = 0; v < 4; ++v) {
          int r = lg * 4 + v, c = n * 16 + lr;
          if (k0 + c > qw + r) sacc[n][v] = -1e30f;
        }
    }
    // ---- online softmax: max only (sum comes from the ones-row MFMA) ----
    float corr[4], p[4][4];
#pragma unroll
    for (int v = 0; v < 4; ++v) {
      float mv = fmaxf(fmaxf(sacc[0][v], sacc[1][v]), fmaxf(sacc[2][v], sacc[3][v]));
#pragma unroll
      for (int msk = 1; msk < 16; msk <<= 1) mv = fmaxf(mv, __shfl_xor(mv, msk));
      float mt = fmaxf(mrow[v], mv);
      corr[v] = EXP2F(mrow[v] - mt);
#pragma unroll
      for (int n = 0; n < 4; ++n) p[n][v] = EXP2F(sacc[n][v] - mt);
      mrow[v] = mt;
    }
#pragma unroll
    for (int dn = 0; dn < 9; ++dn)
#pragma unroll
      for (int v = 0; v < 4; ++v) oacc[dn][v] *= corr[v];
    // ---- P -> LDS (per-wave, padded) ----
#pragma unroll
    for (int v = 0; v < 4; ++v)
#pragma unroll
      for (int n = 0; n < 4; ++n)
        Ps[w][(lg * 4 + v) * 72 + n * 16 + lr] = (bf16)p[n][v];
    // ---- PV: oacc[dn] += P[16x64] @ V^T; dn=8 hits the ones-row => l ----
    __builtin_amdgcn_s_setprio(1);
#pragma unroll
    for (int kc = 0; kc < 2; ++kc) {
      bf16x8 pf = *(const bf16x8*)(Ps[w] + lr * 72 + kc * 32 + lg * 8);
#pragma unroll
      for (int dn = 0; dn < 9; ++dn) {
        int d = dn * 16 + lr;
        bf16x8 vf = *(const bf16x8*)(Vs + d * KVB + (((kc * 4 + lg) ^ lr7) << 3));
        oacc[dn] = __builtin_amdgcn_mfma_f32_16x16x32_bf16(pf, vf, oacc[dn], 0, 0, 0);
      }
    }
    __builtin_amdgcn_s_setprio(0);
  }
  // ---- epilogue: l lives in column d=128 (lanes lr==0); broadcast + divide ----
  float rl[4];
#pragma unroll
  for (int v = 0; v < 4; ++v) {
    float lv = __shfl(oacc[8][v], lg * 16);
    rl[v] = 1.0f / lv;
  }
#pragma unroll
  for (int dn = 0; dn < 8; ++dn)
#pragma unroll
    for (int v = 0; v < 4; ++v) {
      int r = lg * 4 + v;
      float o = oacc[dn][v] * rl[v];
      att[((long)(b * S_ + qw + r)) * 2048 + h * 128 + dn * 16 + lr] = (bf16)o;
    }
}

extern "C" void kernel_launch(void* const* d_in, const int* in_sizes, int n_in,
                              void* d_out, int out_size, void* d_ws, size_t ws_size,
                              hipStream_t stream) {
  const float* x        = (const float*)d_in[0];
  const int* pos        = (const int*)d_in[1];   // harness passes integers as int32
  const float* Wqa      = (const float*)d_in[2];
  const float* g_qa     = (const float*)d_in[3];
  const float* Wqb      = (const float*)d_in[4];
  const float* Wkva     = (const float*)d_in[5];
  const float* g_kva    = (const float*)d_in[6];
  const float* Wkvb     = (const float*)d_in[7];
  const float* Wo       = (const float*)d_in[8];
  const float* cosT     = (const float*)d_in[9];
  const float* sinT     = (const float*)d_in[10];
  float* out            = (float*)d_out;

  // ---- workspace layout ----
  size_t off = 0;
  char* wsp = (char*)d_ws;
  auto alloc = [&](size_t n) { void* p = wsp + off; off += (n + 255) & ~(size_t)255; return p; };
  bf16*  Wqa_t  = (bf16*) alloc((size_t)QR * HD * 2);      // contiguous with
  bf16*  Wkva_t = (bf16*) alloc((size_t)640 * HD * 2);     //  ... Wqa_t (concat Bt)
  bf16*  Wqb_t  = (bf16*) alloc((size_t)NQB * QR * 2);
  bf16*  Wkvb_t = (bf16*) alloc((size_t)NKVB * KVR * 2);
  bf16*  Wo_t   = (bf16*) alloc((size_t)HD * HD * 2);
  bf16*  x_bf   = (bf16*) alloc((size_t)NTOK * HD * 2);
  bf16*  q_bhsd = (bf16*) alloc((size_t)B_ * NH * S_ * DQK * 2);
  bf16*  k_bhsd = (bf16*) alloc((size_t)B_ * NH * S_ * DQK * 2);
  bf16*  v_rows = (bf16*) alloc((size_t)NTOK * 2048 * 2);
  bf16*  v_t    = (bf16*) alloc((size_t)B_ * NH * DV * S_ * 2);
  bf16*  att    = (bf16*) alloc((size_t)NTOK * 2048 * 2);
  char*  T      = (char*) alloc((size_t)33554432);         // 32 MB transient
  bf16*  xa  = (bf16*)T;                        // [NTOK][2176] = 17.8 MB
  bf16*  q_n = (bf16*)(T + 18874368);           // [NTOK][1536] = 12.6 MB
  bf16*  kv_l = (bf16*)(T + 18874368 + 12582912); // [NTOK][512] = 4.2 MB
  if (ws_size < off) return;

  cvt_bf16<<<(NTOK * HD / 4 + 255) / 256, 256, 0, stream>>>(x, x_bf, (long)NTOK * HD);
  transpose_cvt<<<dim3(QR / 32, HD / 32), 256, 0, stream>>>(Wqa, Wqa_t, HD, QR, QR);
  transpose_cvt<<<dim3(640 / 32, HD / 32), 256, 0, stream>>>(Wkva, Wkva_t, HD, 576, 640);
  transpose_cvt<<<dim3(NQB / 32, QR / 32), 256, 0, stream>>>(Wqb, Wqb_t, QR, NQB, NQB);
  transpose_cvt<<<dim3(NKVB / 32, KVR / 32), 256, 0, stream>>>(Wkvb, Wkvb_t, KVR, NKVB, NKVB);
  transpose_cvt<<<dim3(HD / 32, HD / 32), 256, 0, stream>>>(Wo, Wo_t, HD, HD, HD);
  // ---- combined first-stage GEMM: xa = x_bf @ [Wqa | Wkva] ----
  gemm2p<bf16><<<dim3(NQKVA / 128, NTOK / 256), 512, 0, stream>>>(x_bf, Wqa_t, xa, NTOK, NQKVA, HD);
  // ---- merged norms + rope prep ----
  norm_prep<<<NTOK, 256, 0, stream>>>(xa, g_qa, g_kva, pos, cosT, sinT, q_n, kv_l, k_bhsd);
  // ---- Q path ----
  gemm2p_qf<<<dim3(NQB / 128, NTOK / 256), 512, 0, stream>>>(q_n, Wqb_t, pos, cosT, sinT, q_bhsd);
  // ---- KV path ----
  gemm2p_kvb<<<dim3(NKVB / 128, NTOK / 256), 512, 0, stream>>>(kv_l, Wkvb_t, k_bhsd, v_rows);
  v_trans<<<dim3(S_ / 32, DV / 32, B_ * NH), 256, 0, stream>>>(v_rows, v_t);
  // ---- attention + output projection ----
  flash2<<<1024, 256, 0, stream>>>(q_bhsd, k_bhsd, v_t, att);
  gemm2p<float><<<dim3(HD / 128, NTOK / 256), 512, 0, stream>>>(att, Wo_t, out, NTOK, HD, HD);
}

// Round 10
// 325.345 us; speedup vs baseline: 1.0593x; 1.0593x over previous
//
#include <hip/hip_runtime.h>
#include <hip/hip_bf16.h>

typedef __bf16 bf16;
typedef __bf16 bf16x8 __attribute__((ext_vector_type(8)));
typedef __bf16 bf16x4 __attribute__((ext_vector_type(4)));
typedef float f32x4 __attribute__((ext_vector_type(4)));

#define B_    2
#define S_    2048
#define HD    2048
#define NH    16
#define DQK   192
#define DV    128
#define QR    1536
#define KVR   512
#define NTOK  4096
#define NKVB  4096   /* N_HEADS*(D_NOPE+D_V) */
#define NQB   3072   /* N_HEADS*D_QK */
#define NQKVA 2176   /* QR + 640 (padded kv_a) */

#define EXP2F(x) __builtin_amdgcn_exp2f(x)

static __device__ __forceinline__ void gload16(const void* g, void* l) {
  __builtin_amdgcn_global_load_lds(
      (const __attribute__((address_space(1))) void*)g,
      (__attribute__((address_space(3))) void*)l, 16, 0, 0);
}

// ---------------- f32 -> bf16 convert ----------------
__global__ __launch_bounds__(256) void cvt_bf16(const float* __restrict__ in,
                                                bf16* __restrict__ out, long n) {
  long i = ((long)blockIdx.x * 256 + threadIdx.x) * 4;
  if (i + 3 < n) {
    float4 v = *(const float4*)(in + i);
    bf16x4 o = {(bf16)v.x, (bf16)v.y, (bf16)v.z, (bf16)v.w};
    *(bf16x4*)(out + i) = o;
  }
}

// ---------------- merged weight transposes: 5 segments, one launch ------------
// f32 [R][C] -> bf16 [Np][R], zero-pad cols >= C.
struct TransArgs {
  const float *s0, *s1, *s2, *s3, *s4;
  bf16 *d0, *d1, *d2, *d3, *d4;
};
__global__ __launch_bounds__(256) void transpose_all(TransArgs a) {
  __shared__ float tile[32][33];
  int bid = blockIdx.x;
  int seg, rel;
  if      (bid < 3072)  { seg = 0; rel = bid; }
  else if (bid < 4352)  { seg = 1; rel = bid - 3072; }
  else if (bid < 8960)  { seg = 2; rel = bid - 4352; }
  else if (bid < 11008) { seg = 3; rel = bid - 8960; }
  else                  { seg = 4; rel = bid - 11008; }
  const float* in = seg == 0 ? a.s0 : seg == 1 ? a.s1 : seg == 2 ? a.s2 : seg == 3 ? a.s3 : a.s4;
  bf16* out       = seg == 0 ? a.d0 : seg == 1 ? a.d1 : seg == 2 ? a.d2 : seg == 3 ? a.d3 : a.d4;
  int R   = seg == 0 ? 2048 : seg == 1 ? 2048 : seg == 2 ? 1536 : seg == 3 ? 512 : 2048;
  int C   = seg == 0 ? 1536 : seg == 1 ? 576  : seg == 2 ? 3072 : seg == 3 ? 4096 : 2048;
  int Np  = seg == 0 ? 1536 : seg == 1 ? 640  : seg == 2 ? 3072 : seg == 3 ? 4096 : 2048;
  int nbx = seg == 0 ? 48   : seg == 1 ? 20   : seg == 2 ? 96   : seg == 3 ? 128 : 64;
  int c0 = (rel % nbx) * 32;
  int r0 = (rel / nbx) * 32;
  int tx = threadIdx.x & 31, ty = threadIdx.x >> 5;
#pragma unroll
  for (int i = 0; i < 4; ++i) {
    int r = r0 + ty + i * 8, c = c0 + tx;
    tile[ty + i * 8][tx] = (c < C) ? in[(long)r * C + c] : 0.f;
  }
  __syncthreads();
#pragma unroll
  for (int i = 0; i < 4; ++i) {
    int oc = c0 + ty + i * 8;
    if (oc < Np) out[(long)oc * R + r0 + tx] = (bf16)tile[tx][ty + i * 8];
  }
}

// ============ shared GEMM core: 128x128 tile, BK=64, XOR chunk swizzle ========
#define GEMM_CORE(A, Bt, K)                                                    \
  __shared__ bf16 As[128 * 64];                                                \
  __shared__ bf16 Bs[128 * 64];                                                \
  const int t = threadIdx.x;                                                   \
  const int l = t & 63;                                                        \
  const int w = t >> 6;                                                        \
  const int m0 = blockIdx.y * 128;                                             \
  const int n0 = blockIdx.x * 128;                                             \
  const int wr = (w >> 1) * 64;                                                \
  const int wc = (w & 1) * 64;                                                 \
  const int lr = l & 15;                                                       \
  const int lg = l >> 4;                                                       \
  f32x4 acc[4][4] = {};                                                        \
  for (int k0 = 0; k0 < (K); k0 += 64) {                                       \
    __syncthreads();                                                           \
    _Pragma("unroll")                                                          \
    for (int j = 0; j < 4; ++j) {                                              \
      int s = j * 256 + t;                                                     \
      int row = s >> 3, sc = s & 7;                                            \
      int c = sc ^ (row & 7);                                                  \
      gload16((A) + (long)(m0 + row) * (K) + k0 + c * 8,                       \
              As + (j * 256 + w * 64) * 8);                                    \
      gload16((Bt) + (long)(n0 + row) * (K) + k0 + c * 8,                      \
              Bs + (j * 256 + w * 64) * 8);                                    \
    }                                                                          \
    __syncthreads();                                                           \
    _Pragma("unroll")                                                          \
    for (int kh = 0; kh < 2; ++kh) {                                           \
      bf16x8 af[4], bfr[4];                                                    \
      _Pragma("unroll")                                                        \
      for (int m = 0; m < 4; ++m) {                                            \
        int row = wr + m * 16 + lr;                                            \
        af[m] = *(const bf16x8*)(As + row * 64 + (((kh * 4 + lg) ^ (row & 7)) << 3)); \
      }                                                                        \
      _Pragma("unroll")                                                        \
      for (int n = 0; n < 4; ++n) {                                            \
        int row = wc + n * 16 + lr;                                            \
        bfr[n] = *(const bf16x8*)(Bs + row * 64 + (((kh * 4 + lg) ^ (row & 7)) << 3)); \
      }                                                                        \
      _Pragma("unroll")                                                        \
      for (int m = 0; m < 4; ++m)                                              \
        _Pragma("unroll")                                                      \
        for (int n = 0; n < 4; ++n)                                            \
          acc[m][n] = __builtin_amdgcn_mfma_f32_16x16x32_bf16(af[m], bfr[n], acc[m][n], 0, 0, 0); \
    }                                                                          \
  }

// ---------------- generic GEMM: C[M][N] = A @ Bt^T ----------------------------
template <typename CT>
__global__ __launch_bounds__(256) void gemm_bf16(const bf16* __restrict__ A,
                                                 const bf16* __restrict__ Bt,
                                                 CT* __restrict__ C,
                                                 int M, int N, int K) {
  GEMM_CORE(A, Bt, K)
#pragma unroll
  for (int m = 0; m < 4; ++m)
#pragma unroll
    for (int n = 0; n < 4; ++n)
#pragma unroll
      for (int v = 0; v < 4; ++v) {
        int row = m0 + wr + m * 16 + lg * 4 + v;
        int col = n0 + wc + n * 16 + lr;
        C[(long)row * N + col] = (CT)acc[m][n][v];
      }
}

// ---------------- fused q_f GEMM: epilogue applies RoPE + SCALE*LOG2E ---------
__global__ __launch_bounds__(256) void gemm_qf(const bf16* __restrict__ A,
                                               const bf16* __restrict__ Bt,
                                               const int* __restrict__ pos,
                                               const float* __restrict__ cosT,
                                               const float* __restrict__ sinT,
                                               bf16* __restrict__ q_bhsd) {
  const float SCALE = 0.07216878364870323f * 1.4426950408889634f;
  GEMM_CORE(A, Bt, QR)
  int c0 = n0 + wc;
  int h = c0 / 192;
  int part = c0 - h * 192;            // 0, 64, or 128 (wave-uniform)
#pragma unroll
  for (int m = 0; m < 4; ++m)
#pragma unroll
    for (int v = 0; v < 4; ++v) {
      int row = m0 + wr + m * 16 + lg * 4 + v;
      int b = row >> 11, s = row & (S_ - 1);
      long base = ((long)(b * NH + h) * S_ + s) * DQK;
      if (part < 128) {
#pragma unroll
        for (int n = 0; n < 4; ++n)
          q_bhsd[base + part + n * 16 + lr] = (bf16)(acc[m][n][v] * SCALE);
      } else {
        int p = pos[s] & (S_ - 1);
        float c_lo = cosT[p * 32 + lr],      s_lo = sinT[p * 32 + lr];
        float c_hi = cosT[p * 32 + 16 + lr], s_hi = sinT[p * 32 + 16 + lr];
        float o0 = acc[m][0][v] * c_lo - acc[m][2][v] * s_lo;
        float o1 = acc[m][1][v] * c_hi - acc[m][3][v] * s_hi;
        float o2 = acc[m][0][v] * s_lo + acc[m][2][v] * c_lo;
        float o3 = acc[m][1][v] * s_hi + acc[m][3][v] * c_hi;
        q_bhsd[base + 128 + lr] = (bf16)(o0 * SCALE);
        q_bhsd[base + 144 + lr] = (bf16)(o1 * SCALE);
        q_bhsd[base + 160 + lr] = (bf16)(o2 * SCALE);
        q_bhsd[base + 176 + lr] = (bf16)(o3 * SCALE);
      }
    }
}

// ---------------- fused kv_b GEMM: k-part -> k_bhsd, v-part -> v_rows ---------
__global__ __launch_bounds__(256) void gemm_kvb(const bf16* __restrict__ A,
                                                const bf16* __restrict__ Bt,
                                                bf16* __restrict__ k_bhsd,
                                                bf16* __restrict__ v_rows) {
  GEMM_CORE(A, Bt, KVR)
  int c0 = n0 + wc;
  int h = c0 >> 8;
  int dbase = c0 & 64;
  bool vpart = (c0 >> 7) & 1;
#pragma unroll
  for (int m = 0; m < 4; ++m)
#pragma unroll
    for (int v = 0; v < 4; ++v) {
      int row = m0 + wr + m * 16 + lg * 4 + v;
      int b = row >> 11, s = row & (S_ - 1);
      if (!vpart) {
        long base = ((long)(b * NH + h) * S_ + s) * DQK + dbase;
#pragma unroll
        for (int n = 0; n < 4; ++n)
          k_bhsd[base + n * 16 + lr] = (bf16)acc[m][n][v];
      } else {
        long base = (long)row * 2048 + h * 128 + dbase;
#pragma unroll
        for (int n = 0; n < 4; ++n)
          v_rows[base + n * 16 + lr] = (bf16)acc[m][n][v];
      }
    }
}

// ---------------- merged norm+prep: waves 0-2 q-RMSNorm, wave 3 kv+rope -------
__global__ __launch_bounds__(256) void norm_prep(const bf16* __restrict__ xa,   // [NTOK][2176]
                                                 const float* __restrict__ g_qa,
                                                 const float* __restrict__ g_kva,
                                                 const int* __restrict__ pos,
                                                 const float* __restrict__ cosT,
                                                 const float* __restrict__ sinT,
                                                 bf16* __restrict__ q_n,       // [NTOK][1536]
                                                 bf16* __restrict__ kv_l,      // [NTOK][512]
                                                 bf16* __restrict__ k_bhsd) {  // [B][H][S][192]
  int row = blockIdx.x;
  int t = threadIdx.x;
  int b = row >> 11, s = row & (S_ - 1);
  const bf16* xr = xa + (long)row * NQKVA;
  __shared__ float red[3];
  __shared__ bf16 rope_s[64];
  float vf[8];
  if (t < 192) {
    bf16x8 vv = *(const bf16x8*)(xr + t * 8);
    float ss = 0.f;
#pragma unroll
    for (int e = 0; e < 8; ++e) { vf[e] = (float)vv[e]; ss += vf[e] * vf[e]; }
#pragma unroll
    for (int m = 1; m < 64; m <<= 1) ss += __shfl_xor(ss, m);
    if ((t & 63) == 0) red[t >> 6] = ss;
  } else {
    int tt = t - 192;
    const bf16* xl = xr + QR;
    bf16x8 vv = *(const bf16x8*)(xl + tt * 8);
    float ss = 0.f;
#pragma unroll
    for (int e = 0; e < 8; ++e) { vf[e] = (float)vv[e]; ss += vf[e] * vf[e]; }
#pragma unroll
    for (int m = 1; m < 64; m <<= 1) ss += __shfl_xor(ss, m);
    float rs = rsqrtf(ss / KVR + 1e-5f);
    bf16x8 o;
#pragma unroll
    for (int e = 0; e < 8; ++e) o[e] = (bf16)(vf[e] * rs * g_kva[tt * 8 + e]);
    *(bf16x8*)(kv_l + (long)row * KVR + tt * 8) = o;
    if (tt < 32) {
      int p = pos[s] & (S_ - 1);
      float c = cosT[p * 32 + tt], sn = sinT[p * 32 + tt];
      float x0 = (float)xl[512 + tt], x1 = (float)xl[544 + tt];
      rope_s[tt] = (bf16)(x0 * c - x1 * sn);
      rope_s[32 + tt] = (bf16)(x0 * sn + x1 * c);
    }
  }
  __syncthreads();
  if (t < 192) {
    float ss = red[0] + red[1] + red[2];
    float rs = rsqrtf(ss / QR + 1e-5f);
    bf16x8 o;
#pragma unroll
    for (int e = 0; e < 8; ++e) o[e] = (bf16)(vf[e] * rs * g_qa[t * 8 + e]);
    *(bf16x8*)(q_n + (long)row * QR + t * 8) = o;
  } else {
    int tt = t - 192;
    bf16x8 rv = *(const bf16x8*)&rope_s[(tt & 7) * 8];
    long base0 = ((long)(b * NH + (tt >> 3)) * S_ + s) * DQK + 128 + (tt & 7) * 8;
    long base1 = ((long)(b * NH + 8 + (tt >> 3)) * S_ + s) * DQK + 128 + (tt & 7) * 8;
    *(bf16x8*)(k_bhsd + base0) = rv;
    *(bf16x8*)(k_bhsd + base1) = rv;
  }
}

// ---------------- V transpose: v_rows [NTOK][2048] -> v_t [BH][128][S] --------
__global__ __launch_bounds__(256) void v_trans(const bf16* __restrict__ v_rows,
                                               bf16* __restrict__ v_t) {
  __shared__ bf16 tile[32][33];
  int st = blockIdx.x, dt = blockIdx.y, bh = blockIdx.z;
  int b = bh >> 4, h = bh & 15;
  int tx = threadIdx.x & 31, ty = threadIdx.x >> 5;
#pragma unroll
  for (int i = 0; i < 4; ++i) {
    int s = st * 32 + ty + i * 8, d = dt * 32 + tx;
    tile[ty + i * 8][tx] = v_rows[((long)(b * S_ + s)) * 2048 + h * 128 + d];
  }
  __syncthreads();
#pragma unroll
  for (int i = 0; i < 4; ++i) {
    int d = dt * 32 + ty + i * 8, s = st * 32 + tx;
    v_t[((long)bh * DV + d) * S_ + s] = tile[tx][ty + i * 8];
  }
}

// ---------------- flash v2c: ones-row l; exp2 softmax; defer-max rescale ------
// scores in log2-domain. Vs rows 128..143: ones-row trick gives l in oacc[8].
// Defer-max (T13): skip corr/rescale when no row max grew by >8 (P <= 2^8).
#define QBLK 64
#define KVB  64
#define DVP  144
__global__ __launch_bounds__(256) void flash2(const bf16* __restrict__ q_bhsd,
                                              const bf16* __restrict__ k_bhsd,
                                              const bf16* __restrict__ v_t,
                                              bf16* __restrict__ att) {  // [NTOK][2048]
  __shared__ bf16 Ks[KVB * DQK];      // 24 KB, swizzled 16B chunks
  __shared__ bf16 Vs[DVP * KVB];      // 18 KB, rows 0-127 staged, 128-143 const
  __shared__ bf16 Ps[4][16 * 72];     // 9 KB, per-wave P, padded to 72
  int bid = blockIdx.x;
  int bh = bid & 31;                  // head-of-batch: fixes XCD = bh%8
  int qt = 31 - (bid >> 5);           // heaviest (most k-tiles) first
  int b = bh >> 4, h = bh & 15;
  int q0 = qt * QBLK;
  int t = threadIdx.x;
  int w = t >> 6, l = t & 63;
  int lr = l & 15, lg = l >> 4;
  int qw = q0 + w * 16;               // this wave's first q row

  const bf16* Qb = q_bhsd + (long)bh * S_ * DQK;
  const bf16* Kb = k_bhsd + (long)bh * S_ * DQK;
  const bf16* Vb = v_t + (long)bh * DV * S_;

  // init ones/zero rows of Vs (persist across tiles; staging never touches them)
  if (t < 128) {
    int rr = 128 + (t >> 3), cc = (t & 7) * 8;
    bf16 val = (bf16)((rr == 128) ? 1.0f : 0.0f);
    bf16x8 vvv = {val, val, val, val, val, val, val, val};
    *(bf16x8*)(Vs + rr * KVB + cc) = vvv;
  }

  bf16x8 qf[6];
#pragma unroll
  for (int t6 = 0; t6 < 6; ++t6)
    qf[t6] = *(const bf16x8*)(Qb + (long)(qw + lr) * DQK + t6 * 32 + lg * 8);

  f32x4 oacc[9] = {};                 // [0..7] output, [8] = l (ones-row)
  float mrow[4] = {-1e30f, -1e30f, -1e30f, -1e30f};
  const int lr7 = lr & 7;

  int nkt = qt + 1;
  for (int kt = 0; kt < nkt; ++kt) {
    int k0 = kt * KVB;
    __syncthreads();
    // stage K: 1536 chunks (6 x 256); slot s holds global chunk (r, c^(r&7))
#pragma unroll
    for (int j = 0; j < 6; ++j) {
      int s = j * 256 + t;
      int r = s / 24, c1 = s - r * 24;
      int c = c1 ^ (r & 7);
      gload16(Kb + (long)(k0 + r) * DQK + c * 8, Ks + (j * 256 + w * 64) * 8);
    }
    // stage V: 1024 chunks (4 x 256), rows 0..127 only
#pragma unroll
    for (int j = 0; j < 4; ++j) {
      int s = j * 256 + t;
      int d = s >> 3, c1 = s & 7;
      int c = c1 ^ (d & 7);
      gload16(Vb + (long)d * S_ + k0 + c * 8, Vs + (j * 256 + w * 64) * 8);
    }
    __syncthreads();
    if (k0 > qw + 15) continue;       // fully masked for this wave

    // ---- QK^T: sacc[n] = scores[q=lg*4+v][k=n*16+lr] (log2-domain) ----
    f32x4 sacc[4] = {};
#pragma unroll
    for (int n = 0; n < 4; ++n) {
      int rk = n * 16 + lr;
#pragma unroll
      for (int t6 = 0; t6 < 6; ++t6) {
        bf16x8 kf = *(const bf16x8*)(Ks + rk * DQK + (((t6 * 4 + lg) ^ lr7) << 3));
        sacc[n] = __builtin_amdgcn_mfma_f32_16x16x32_bf16(qf[t6], kf, sacc[n], 0, 0, 0);
      }
    }
    // ---- causal mask (diagonal tiles only) ----
    if (k0 + KVB - 1 > qw) {
#pragma unroll
      for (int n = 0; n < 4; ++n)
#pragma unroll
        for (int v = 0; v < 4; ++v) {
          int r = lg * 4 + v, c = n * 16 + lr;
          if (k0 + c > qw + r) sacc[n][v] = -1e30f;
        }
    }
    // ---- tile row-max ----
    float mv[4];
#pragma unroll
    for (int v = 0; v < 4; ++v) {
      mv[v] = fmaxf(fmaxf(sacc[0][v], sacc[1][v]), fmaxf(sacc[2][v], sacc[3][v]));
#pragma unroll
      for (int msk = 1; msk < 16; msk <<= 1) mv[v] = fmaxf(mv[v], __shfl_xor(mv[v], msk));
    }
    // ---- defer-max: rescale only if some row max grew by > 8 (log2) ----
    bool grow = (mv[0] > mrow[0] + 8.f) | (mv[1] > mrow[1] + 8.f) |
                (mv[2] > mrow[2] + 8.f) | (mv[3] > mrow[3] + 8.f);
    if (__any(grow)) {
      float corr[4];
#pragma unroll
      for (int v = 0; v < 4; ++v) {
        float mt = fmaxf(mrow[v], mv[v]);
        corr[v] = EXP2F(mrow[v] - mt);
        mrow[v] = mt;
      }
#pragma unroll
      for (int dn = 0; dn < 9; ++dn)
#pragma unroll
        for (int v = 0; v < 4; ++v) oacc[dn][v] *= corr[v];
    }
    // ---- P = exp2(s - mrow); P -> LDS (per-wave, padded) ----
#pragma unroll
    for (int v = 0; v < 4; ++v)
#pragma unroll
      for (int n = 0; n < 4; ++n)
        Ps[w][(lg * 4 + v) * 72 + n * 16 + lr] = (bf16)EXP2F(sacc[n][v] - mrow[v]);
    // ---- PV: oacc[dn] += P[16x64] @ V^T; dn=8 hits the ones-row => l ----
#pragma unroll
    for (int kc = 0; kc < 2; ++kc) {
      bf16x8 pf = *(const bf16x8*)(Ps[w] + lr * 72 + kc * 32 + lg * 8);
#pragma unroll
      for (int dn = 0; dn < 9; ++dn) {
        int d = dn * 16 + lr;
        bf16x8 vf = *(const bf16x8*)(Vs + d * KVB + (((kc * 4 + lg) ^ lr7) << 3));
        oacc[dn] = __builtin_amdgcn_mfma_f32_16x16x32_bf16(pf, vf, oacc[dn], 0, 0, 0);
      }
    }
  }
  // ---- epilogue: l lives in column d=128 (lanes lr==0); broadcast + divide ----
  float rl[4];
#pragma unroll
  for (int v = 0; v < 4; ++v) {
    float lv = __shfl(oacc[8][v], lg * 16);
    rl[v] = 1.0f / lv;
  }
#pragma unroll
  for (int dn = 0; dn < 8; ++dn)
#pragma unroll
    for (int v = 0; v < 4; ++v) {
      int r = lg * 4 + v;
      float o = oacc[dn][v] * rl[v];
      att[((long)(b * S_ + qw + r)) * 2048 + h * 128 + dn * 16 + lr] = (bf16)o;
    }
}

extern "C" void kernel_launch(void* const* d_in, const int* in_sizes, int n_in,
                              void* d_out, int out_size, void* d_ws, size_t ws_size,
                              hipStream_t stream) {
  const float* x        = (const float*)d_in[0];
  const int* pos        = (const int*)d_in[1];   // harness passes integers as int32
  const float* Wqa      = (const float*)d_in[2];
  const float* g_qa     = (const float*)d_in[3];
  const float* Wqb      = (const float*)d_in[4];
  const float* Wkva     = (const float*)d_in[5];
  const float* g_kva    = (const float*)d_in[6];
  const float* Wkvb     = (const float*)d_in[7];
  const float* Wo       = (const float*)d_in[8];
  const float* cosT     = (const float*)d_in[9];
  const float* sinT     = (const float*)d_in[10];
  float* out            = (float*)d_out;

  // ---- workspace layout ----
  size_t off = 0;
  char* wsp = (char*)d_ws;
  auto alloc = [&](size_t n) { void* p = wsp + off; off += (n + 255) & ~(size_t)255; return p; };
  bf16*  Wqa_t  = (bf16*) alloc((size_t)QR * HD * 2);      // contiguous with
  bf16*  Wkva_t = (bf16*) alloc((size_t)640 * HD * 2);     //  ... Wqa_t (concat Bt)
  bf16*  Wqb_t  = (bf16*) alloc((size_t)NQB * QR * 2);
  bf16*  Wkvb_t = (bf16*) alloc((size_t)NKVB * KVR * 2);
  bf16*  Wo_t   = (bf16*) alloc((size_t)HD * HD * 2);
  bf16*  x_bf   = (bf16*) alloc((size_t)NTOK * HD * 2);
  bf16*  q_bhsd = (bf16*) alloc((size_t)B_ * NH * S_ * DQK * 2);
  bf16*  k_bhsd = (bf16*) alloc((size_t)B_ * NH * S_ * DQK * 2);
  bf16*  v_rows = (bf16*) alloc((size_t)NTOK * 2048 * 2);
  bf16*  v_t    = (bf16*) alloc((size_t)B_ * NH * DV * S_ * 2);
  bf16*  att    = (bf16*) alloc((size_t)NTOK * 2048 * 2);
  char*  T      = (char*) alloc((size_t)33554432);         // 32 MB transient
  bf16*  xa  = (bf16*)T;                        // [NTOK][2176] = 17.8 MB
  bf16*  q_n = (bf16*)(T + 18874368);           // [NTOK][1536] = 12.6 MB
  bf16*  kv_l = (bf16*)(T + 18874368 + 12582912); // [NTOK][512] = 4.2 MB
  if (ws_size < off) return;

  cvt_bf16<<<(NTOK * HD / 4 + 255) / 256, 256, 0, stream>>>(x, x_bf, (long)NTOK * HD);
  TransArgs ta = {Wqa, Wkva, Wqb, Wkvb, Wo, Wqa_t, Wkva_t, Wqb_t, Wkvb_t, Wo_t};
  transpose_all<<<15104, 256, 0, stream>>>(ta);
  // ---- combined first-stage GEMM: xa = x_bf @ [Wqa | Wkva] ----
  gemm_bf16<bf16><<<dim3(NQKVA / 128, NTOK / 128), 256, 0, stream>>>(x_bf, Wqa_t, xa, NTOK, NQKVA, HD);
  // ---- merged norms + rope prep ----
  norm_prep<<<NTOK, 256, 0, stream>>>(xa, g_qa, g_kva, pos, cosT, sinT, q_n, kv_l, k_bhsd);
  // ---- Q path ----
  gemm_qf<<<dim3(NQB / 128, NTOK / 128), 256, 0, stream>>>(q_n, Wqb_t, pos, cosT, sinT, q_bhsd);
  // ---- KV path ----
  gemm_kvb<<<dim3(NKVB / 128, NTOK / 128), 256, 0, stream>>>(kv_l, Wkvb_t, k_bhsd, v_rows);
  v_trans<<<dim3(S_ / 32, DV / 32, B_ * NH), 256, 0, stream>>>(v_rows, v_t);
  // ---- attention + output projection ----
  flash2<<<1024, 256, 0, stream>>>(q_bhsd, k_bhsd, v_t, att);
  gemm_bf16<float><<<dim3(HD / 128, NTOK / 128), 256, 0, stream>>>(att, Wo_t, out, NTOK, HD, HD);
}

// Round 11
// 320.117 us; speedup vs baseline: 1.0766x; 1.0163x over previous
//
#include <hip/hip_runtime.h>
#include <hip/hip_bf16.h>

typedef __bf16 bf16;
typedef __bf16 bf16x8 __attribute__((ext_vector_type(8)));
typedef __bf16 bf16x4 __attribute__((ext_vector_type(4)));
typedef float f32x4 __attribute__((ext_vector_type(4)));

#define B_    2
#define S_    2048
#define HD    2048
#define NH    16
#define DQK   192
#define DV    128
#define QR    1536
#define KVR   512
#define NTOK  4096
#define NKVB  4096   /* N_HEADS*(D_NOPE+D_V) */
#define NQB   3072   /* N_HEADS*D_QK */
#define NQKVA 2176   /* QR + 640 (padded kv_a) */

#define EXP2F(x) __builtin_amdgcn_exp2f(x)

static __device__ __forceinline__ void gload16(const void* g, void* l) {
  __builtin_amdgcn_global_load_lds(
      (const __attribute__((address_space(1))) void*)g,
      (__attribute__((address_space(3))) void*)l, 16, 0, 0);
}

// ---------------- f32 -> bf16 convert ----------------
__global__ __launch_bounds__(256) void cvt_bf16(const float* __restrict__ in,
                                                bf16* __restrict__ out, long n) {
  long i = ((long)blockIdx.x * 256 + threadIdx.x) * 4;
  if (i + 3 < n) {
    float4 v = *(const float4*)(in + i);
    bf16x4 o = {(bf16)v.x, (bf16)v.y, (bf16)v.z, (bf16)v.w};
    *(bf16x4*)(out + i) = o;
  }
}

// ---------------- merged weight transposes: 5 segments, one launch ------------
struct TransArgs {
  const float *s0, *s1, *s2, *s3, *s4;
  bf16 *d0, *d1, *d2, *d3, *d4;
};
__global__ __launch_bounds__(256) void transpose_all(TransArgs a) {
  __shared__ float tile[32][33];
  int bid = blockIdx.x;
  int seg, rel;
  if      (bid < 3072)  { seg = 0; rel = bid; }
  else if (bid < 4352)  { seg = 1; rel = bid - 3072; }
  else if (bid < 8960)  { seg = 2; rel = bid - 4352; }
  else if (bid < 11008) { seg = 3; rel = bid - 8960; }
  else                  { seg = 4; rel = bid - 11008; }
  const float* in = seg == 0 ? a.s0 : seg == 1 ? a.s1 : seg == 2 ? a.s2 : seg == 3 ? a.s3 : a.s4;
  bf16* out       = seg == 0 ? a.d0 : seg == 1 ? a.d1 : seg == 2 ? a.d2 : seg == 3 ? a.d3 : a.d4;
  int R   = seg == 0 ? 2048 : seg == 1 ? 2048 : seg == 2 ? 1536 : seg == 3 ? 512 : 2048;
  int C   = seg == 0 ? 1536 : seg == 1 ? 576  : seg == 2 ? 3072 : seg == 3 ? 4096 : 2048;
  int Np  = seg == 0 ? 1536 : seg == 1 ? 640  : seg == 2 ? 3072 : seg == 3 ? 4096 : 2048;
  int nbx = seg == 0 ? 48   : seg == 1 ? 20   : seg == 2 ? 96   : seg == 3 ? 128 : 64;
  int c0 = (rel % nbx) * 32;
  int r0 = (rel / nbx) * 32;
  int tx = threadIdx.x & 31, ty = threadIdx.x >> 5;
#pragma unroll
  for (int i = 0; i < 4; ++i) {
    int r = r0 + ty + i * 8, c = c0 + tx;
    tile[ty + i * 8][tx] = (c < C) ? in[(long)r * C + c] : 0.f;
  }
  __syncthreads();
#pragma unroll
  for (int i = 0; i < 4; ++i) {
    int oc = c0 + ty + i * 8;
    if (oc < Np) out[(long)oc * R + r0 + tx] = (bf16)tile[tx][ty + i * 8];
  }
}

// ============ shared GEMM core: 128x128 tile, BK=64, XOR chunk swizzle ========
#define GEMM_CORE(A, Bt, K)                                                    \
  __shared__ bf16 As[128 * 64];                                                \
  __shared__ bf16 Bs[128 * 64];                                                \
  const int t = threadIdx.x;                                                   \
  const int l = t & 63;                                                        \
  const int w = t >> 6;                                                        \
  const int m0 = blockIdx.y * 128;                                             \
  const int n0 = blockIdx.x * 128;                                             \
  const int wr = (w >> 1) * 64;                                                \
  const int wc = (w & 1) * 64;                                                 \
  const int lr = l & 15;                                                       \
  const int lg = l >> 4;                                                       \
  f32x4 acc[4][4] = {};                                                        \
  for (int k0 = 0; k0 < (K); k0 += 64) {                                       \
    __syncthreads();                                                           \
    _Pragma("unroll")                                                          \
    for (int j = 0; j < 4; ++j) {                                              \
      int s = j * 256 + t;                                                     \
      int row = s >> 3, sc = s & 7;                                            \
      int c = sc ^ (row & 7);                                                  \
      gload16((A) + (long)(m0 + row) * (K) + k0 + c * 8,                       \
              As + (j * 256 + w * 64) * 8);                                    \
      gload16((Bt) + (long)(n0 + row) * (K) + k0 + c * 8,                      \
              Bs + (j * 256 + w * 64) * 8);                                    \
    }                                                                          \
    __syncthreads();                                                           \
    _Pragma("unroll")                                                          \
    for (int kh = 0; kh < 2; ++kh) {                                           \
      bf16x8 af[4], bfr[4];                                                    \
      _Pragma("unroll")                                                        \
      for (int m = 0; m < 4; ++m) {                                            \
        int row = wr + m * 16 + lr;                                            \
        af[m] = *(const bf16x8*)(As + row * 64 + (((kh * 4 + lg) ^ (row & 7)) << 3)); \
      }                                                                        \
      _Pragma("unroll")                                                        \
      for (int n = 0; n < 4; ++n) {                                            \
        int row = wc + n * 16 + lr;                                            \
        bfr[n] = *(const bf16x8*)(Bs + row * 64 + (((kh * 4 + lg) ^ (row & 7)) << 3)); \
      }                                                                        \
      _Pragma("unroll")                                                        \
      for (int m = 0; m < 4; ++m)                                              \
        _Pragma("unroll")                                                      \
        for (int n = 0; n < 4; ++n)                                            \
          acc[m][n] = __builtin_amdgcn_mfma_f32_16x16x32_bf16(af[m], bfr[n], acc[m][n], 0, 0, 0); \
    }                                                                          \
  }

// ---------------- generic GEMM: C[M][N] = A @ Bt^T ----------------------------
template <typename CT>
__global__ __launch_bounds__(256) void gemm_bf16(const bf16* __restrict__ A,
                                                 const bf16* __restrict__ Bt,
                                                 CT* __restrict__ C,
                                                 int M, int N, int K) {
  GEMM_CORE(A, Bt, K)
#pragma unroll
  for (int m = 0; m < 4; ++m)
#pragma unroll
    for (int n = 0; n < 4; ++n)
#pragma unroll
      for (int v = 0; v < 4; ++v) {
        int row = m0 + wr + m * 16 + lg * 4 + v;
        int col = n0 + wc + n * 16 + lr;
        C[(long)row * N + col] = (CT)acc[m][n][v];
      }
}

// ---------------- fused q_f GEMM: epilogue applies RoPE + SCALE*LOG2E ---------
__global__ __launch_bounds__(256) void gemm_qf(const bf16* __restrict__ A,
                                               const bf16* __restrict__ Bt,
                                               const int* __restrict__ pos,
                                               const float* __restrict__ cosT,
                                               const float* __restrict__ sinT,
                                               bf16* __restrict__ q_bhsd) {
  const float SCALE = 0.07216878364870323f * 1.4426950408889634f;
  GEMM_CORE(A, Bt, QR)
  int c0 = n0 + wc;
  int h = c0 / 192;
  int part = c0 - h * 192;            // 0, 64, or 128 (wave-uniform)
#pragma unroll
  for (int m = 0; m < 4; ++m)
#pragma unroll
    for (int v = 0; v < 4; ++v) {
      int row = m0 + wr + m * 16 + lg * 4 + v;
      int b = row >> 11, s = row & (S_ - 1);
      long base = ((long)(b * NH + h) * S_ + s) * DQK;
      if (part < 128) {
#pragma unroll
        for (int n = 0; n < 4; ++n)
          q_bhsd[base + part + n * 16 + lr] = (bf16)(acc[m][n][v] * SCALE);
      } else {
        int p = pos[s] & (S_ - 1);
        float c_lo = cosT[p * 32 + lr],      s_lo = sinT[p * 32 + lr];
        float c_hi = cosT[p * 32 + 16 + lr], s_hi = sinT[p * 32 + 16 + lr];
        float o0 = acc[m][0][v] * c_lo - acc[m][2][v] * s_lo;
        float o1 = acc[m][1][v] * c_hi - acc[m][3][v] * s_hi;
        float o2 = acc[m][0][v] * s_lo + acc[m][2][v] * c_lo;
        float o3 = acc[m][1][v] * s_hi + acc[m][3][v] * c_hi;
        q_bhsd[base + 128 + lr] = (bf16)(o0 * SCALE);
        q_bhsd[base + 144 + lr] = (bf16)(o1 * SCALE);
        q_bhsd[base + 160 + lr] = (bf16)(o2 * SCALE);
        q_bhsd[base + 176 + lr] = (bf16)(o3 * SCALE);
      }
    }
}

// ---------------- fused kv_b GEMM: k-part -> k_bhsd, v-part -> v_t DIRECT -----
// v-part: acc[m][n][0..3] are 4 consecutive tokens at fixed d => bf16x4 store
// straight into v_t [BH][128][S] (transpose for free; v_trans eliminated).
__global__ __launch_bounds__(256) void gemm_kvb(const bf16* __restrict__ A,
                                                const bf16* __restrict__ Bt,
                                                bf16* __restrict__ k_bhsd,
                                                bf16* __restrict__ v_t) {
  GEMM_CORE(A, Bt, KVR)
  int c0 = n0 + wc;
  int h = c0 >> 8;
  int dbase = c0 & 64;
  bool vpart = (c0 >> 7) & 1;
  if (!vpart) {
#pragma unroll
    for (int m = 0; m < 4; ++m)
#pragma unroll
      for (int v = 0; v < 4; ++v) {
        int row = m0 + wr + m * 16 + lg * 4 + v;
        int b = row >> 11, s = row & (S_ - 1);
        long base = ((long)(b * NH + h) * S_ + s) * DQK + dbase;
#pragma unroll
        for (int n = 0; n < 4; ++n)
          k_bhsd[base + n * 16 + lr] = (bf16)acc[m][n][v];
      }
  } else {
#pragma unroll
    for (int m = 0; m < 4; ++m) {
      int row0 = m0 + wr + m * 16 + lg * 4;
      int b = row0 >> 11, s = row0 & (S_ - 1);
#pragma unroll
      for (int n = 0; n < 4; ++n) {
        int d = dbase + n * 16 + lr;
        bf16x4 o = {(bf16)acc[m][n][0], (bf16)acc[m][n][1],
                    (bf16)acc[m][n][2], (bf16)acc[m][n][3]};
        *(bf16x4*)(v_t + ((long)(b * NH + h) * DV + d) * S_ + s) = o;
      }
    }
  }
}

// ---------------- merged norm+prep: waves 0-2 q-RMSNorm, wave 3 kv+rope -------
__global__ __launch_bounds__(256) void norm_prep(const bf16* __restrict__ xa,   // [NTOK][2176]
                                                 const float* __restrict__ g_qa,
                                                 const float* __restrict__ g_kva,
                                                 const int* __restrict__ pos,
                                                 const float* __restrict__ cosT,
                                                 const float* __restrict__ sinT,
                                                 bf16* __restrict__ q_n,       // [NTOK][1536]
                                                 bf16* __restrict__ kv_l,      // [NTOK][512]
                                                 bf16* __restrict__ k_bhsd) {  // [B][H][S][192]
  int row = blockIdx.x;
  int t = threadIdx.x;
  int b = row >> 11, s = row & (S_ - 1);
  const bf16* xr = xa + (long)row * NQKVA;
  __shared__ float red[3];
  __shared__ bf16 rope_s[64];
  float vf[8];
  if (t < 192) {
    bf16x8 vv = *(const bf16x8*)(xr + t * 8);
    float ss = 0.f;
#pragma unroll
    for (int e = 0; e < 8; ++e) { vf[e] = (float)vv[e]; ss += vf[e] * vf[e]; }
#pragma unroll
    for (int m = 1; m < 64; m <<= 1) ss += __shfl_xor(ss, m);
    if ((t & 63) == 0) red[t >> 6] = ss;
  } else {
    int tt = t - 192;
    const bf16* xl = xr + QR;
    bf16x8 vv = *(const bf16x8*)(xl + tt * 8);
    float ss = 0.f;
#pragma unroll
    for (int e = 0; e < 8; ++e) { vf[e] = (float)vv[e]; ss += vf[e] * vf[e]; }
#pragma unroll
    for (int m = 1; m < 64; m <<= 1) ss += __shfl_xor(ss, m);
    float rs = rsqrtf(ss / KVR + 1e-5f);
    bf16x8 o;
#pragma unroll
    for (int e = 0; e < 8; ++e) o[e] = (bf16)(vf[e] * rs * g_kva[tt * 8 + e]);
    *(bf16x8*)(kv_l + (long)row * KVR + tt * 8) = o;
    if (tt < 32) {
      int p = pos[s] & (S_ - 1);
      float c = cosT[p * 32 + tt], sn = sinT[p * 32 + tt];
      float x0 = (float)xl[512 + tt], x1 = (float)xl[544 + tt];
      rope_s[tt] = (bf16)(x0 * c - x1 * sn);
      rope_s[32 + tt] = (bf16)(x0 * sn + x1 * c);
    }
  }
  __syncthreads();
  if (t < 192) {
    float ss = red[0] + red[1] + red[2];
    float rs = rsqrtf(ss / QR + 1e-5f);
    bf16x8 o;
#pragma unroll
    for (int e = 0; e < 8; ++e) o[e] = (bf16)(vf[e] * rs * g_qa[t * 8 + e]);
    *(bf16x8*)(q_n + (long)row * QR + t * 8) = o;
  } else {
    int tt = t - 192;
    bf16x8 rv = *(const bf16x8*)&rope_s[(tt & 7) * 8];
    long base0 = ((long)(b * NH + (tt >> 3)) * S_ + s) * DQK + 128 + (tt & 7) * 8;
    long base1 = ((long)(b * NH + 8 + (tt >> 3)) * S_ + s) * DQK + 128 + (tt & 7) * 8;
    *(bf16x8*)(k_bhsd + base0) = rv;
    *(bf16x8*)(k_bhsd + base1) = rv;
  }
}

// ---------------- flash v4: 8 waves x 16 q-rows (QBLK=128), shared K/V tiles --
// Same per-wave math as proven flash2 (ones-row l, exp2, defer-max); staged
// K/V tile now amortized over 2x the MFMA; 5 gload16/thread/tile (was 10).
// LDS 60KB -> 2 blocks/CU x 8 waves = 16 waves/CU (up from 12).
#define KVB  64
#define DVP  144
__global__ __launch_bounds__(512) void flash4(const bf16* __restrict__ q_bhsd,
                                              const bf16* __restrict__ k_bhsd,
                                              const bf16* __restrict__ v_t,
                                              bf16* __restrict__ att) {  // [NTOK][2048]
  __shared__ bf16 Ks[KVB * DQK];      // 24 KB, swizzled 16B chunks
  __shared__ bf16 Vs[DVP * KVB];      // 18 KB, rows 0-127 staged, 128-143 const
  __shared__ bf16 Ps[8][16 * 72];     // 18 KB, per-wave P, padded to 72
  int bid = blockIdx.x;
  int bh = bid & 31;                  // head-of-batch: fixes XCD = bh%8
  int qt = 15 - (bid >> 5);           // heaviest (most k-tiles) first
  int b = bh >> 4, h = bh & 15;
  int q0 = qt * 128;
  int t = threadIdx.x;
  int w = t >> 6, l = t & 63;
  int lr = l & 15, lg = l >> 4;
  int qw = q0 + w * 16;               // this wave's first q row

  const bf16* Qb = q_bhsd + (long)bh * S_ * DQK;
  const bf16* Kb = k_bhsd + (long)bh * S_ * DQK;
  const bf16* Vb = v_t + (long)bh * DV * S_;

  // init ones/zero rows of Vs (persist across tiles; staging never touches them)
  if (t < 128) {
    int rr = 128 + (t >> 3), cc = (t & 7) * 8;
    bf16 val = (bf16)((rr == 128) ? 1.0f : 0.0f);
    bf16x8 vvv = {val, val, val, val, val, val, val, val};
    *(bf16x8*)(Vs + rr * KVB + cc) = vvv;
  }

  bf16x8 qf[6];
#pragma unroll
  for (int t6 = 0; t6 < 6; ++t6)
    qf[t6] = *(const bf16x8*)(Qb + (long)(qw + lr) * DQK + t6 * 32 + lg * 8);

  f32x4 oacc[9] = {};                 // [0..7] output, [8] = l (ones-row)
  float mrow[4] = {-1e30f, -1e30f, -1e30f, -1e30f};
  const int lr7 = lr & 7;

  int nkt = 2 * qt + 2;
  for (int kt = 0; kt < nkt; ++kt) {
    int k0 = kt * KVB;
    __syncthreads();
    // stage K: 1536 chunks (3 x 512); slot s holds global chunk (r, c^(r&7))
#pragma unroll
    for (int j = 0; j < 3; ++j) {
      int s = j * 512 + t;
      int r = s / 24, c1 = s - r * 24;
      int c = c1 ^ (r & 7);
      gload16(Kb + (long)(k0 + r) * DQK + c * 8, Ks + (j * 512 + w * 64) * 8);
    }
    // stage V: 1024 chunks (2 x 512), rows 0..127 only
#pragma unroll
    for (int j = 0; j < 2; ++j) {
      int s = j * 512 + t;
      int d = s >> 3, c1 = s & 7;
      int c = c1 ^ (d & 7);
      gload16(Vb + (long)d * S_ + k0 + c * 8, Vs + (j * 512 + w * 64) * 8);
    }
    __syncthreads();
    if (k0 > qw + 15) continue;       // fully masked for this wave

    // ---- QK^T: sacc[n] = scores[q=lg*4+v][k=n*16+lr] (log2-domain) ----
    f32x4 sacc[4] = {};
#pragma unroll
    for (int n = 0; n < 4; ++n) {
      int rk = n * 16 + lr;
#pragma unroll
      for (int t6 = 0; t6 < 6; ++t6) {
        bf16x8 kf = *(const bf16x8*)(Ks + rk * DQK + (((t6 * 4 + lg) ^ lr7) << 3));
        sacc[n] = __builtin_amdgcn_mfma_f32_16x16x32_bf16(qf[t6], kf, sacc[n], 0, 0, 0);
      }
    }
    // ---- causal mask (diagonal tiles only) ----
    if (k0 + KVB - 1 > qw) {
#pragma unroll
      for (int n = 0; n < 4; ++n)
#pragma unroll
        for (int v = 0; v < 4; ++v) {
          int r = lg * 4 + v, c = n * 16 + lr;
          if (k0 + c > qw + r) sacc[n][v] = -1e30f;
        }
    }
    // ---- tile row-max ----
    float mv[4];
#pragma unroll
    for (int v = 0; v < 4; ++v) {
      mv[v] = fmaxf(fmaxf(sacc[0][v], sacc[1][v]), fmaxf(sacc[2][v], sacc[3][v]));
#pragma unroll
      for (int msk = 1; msk < 16; msk <<= 1) mv[v] = fmaxf(mv[v], __shfl_xor(mv[v], msk));
    }
    // ---- defer-max: rescale only if some row max grew by > 8 (log2) ----
    bool grow = (mv[0] > mrow[0] + 8.f) | (mv[1] > mrow[1] + 8.f) |
                (mv[2] > mrow[2] + 8.f) | (mv[3] > mrow[3] + 8.f);
    if (__any(grow)) {
      float corr[4];
#pragma unroll
      for (int v = 0; v < 4; ++v) {
        float mt = fmaxf(mrow[v], mv[v]);
        corr[v] = EXP2F(mrow[v] - mt);
        mrow[v] = mt;
      }
#pragma unroll
      for (int dn = 0; dn < 9; ++dn)
#pragma unroll
        for (int v = 0; v < 4; ++v) oacc[dn][v] *= corr[v];
    }
    // ---- P = exp2(s - mrow); P -> LDS (per-wave, padded) ----
#pragma unroll
    for (int v = 0; v < 4; ++v)
#pragma unroll
      for (int n = 0; n < 4; ++n)
        Ps[w][(lg * 4 + v) * 72 + n * 16 + lr] = (bf16)EXP2F(sacc[n][v] - mrow[v]);
    // ---- PV: oacc[dn] += P[16x64] @ V^T; dn=8 hits the ones-row => l ----
#pragma unroll
    for (int kc = 0; kc < 2; ++kc) {
      bf16x8 pf = *(const bf16x8*)(Ps[w] + lr * 72 + kc * 32 + lg * 8);
#pragma unroll
      for (int dn = 0; dn < 9; ++dn) {
        int d = dn * 16 + lr;
        bf16x8 vf = *(const bf16x8*)(Vs + d * KVB + (((kc * 4 + lg) ^ lr7) << 3));
        oacc[dn] = __builtin_amdgcn_mfma_f32_16x16x32_bf16(pf, vf, oacc[dn], 0, 0, 0);
      }
    }
  }
  // ---- epilogue: l lives in column d=128 (lanes lr==0); broadcast + divide ----
  float rl[4];
#pragma unroll
  for (int v = 0; v < 4; ++v) {
    float lv = __shfl(oacc[8][v], lg * 16);
    rl[v] = 1.0f / lv;
  }
#pragma unroll
  for (int dn = 0; dn < 8; ++dn)
#pragma unroll
    for (int v = 0; v < 4; ++v) {
      int r = lg * 4 + v;
      float o = oacc[dn][v] * rl[v];
      att[((long)(b * S_ + qw + r)) * 2048 + h * 128 + dn * 16 + lr] = (bf16)o;
    }
}

extern "C" void kernel_launch(void* const* d_in, const int* in_sizes, int n_in,
                              void* d_out, int out_size, void* d_ws, size_t ws_size,
                              hipStream_t stream) {
  const float* x        = (const float*)d_in[0];
  const int* pos        = (const int*)d_in[1];   // harness passes integers as int32
  const float* Wqa      = (const float*)d_in[2];
  const float* g_qa     = (const float*)d_in[3];
  const float* Wqb      = (const float*)d_in[4];
  const float* Wkva     = (const float*)d_in[5];
  const float* g_kva    = (const float*)d_in[6];
  const float* Wkvb     = (const float*)d_in[7];
  const float* Wo       = (const float*)d_in[8];
  const float* cosT     = (const float*)d_in[9];
  const float* sinT     = (const float*)d_in[10];
  float* out            = (float*)d_out;

  // ---- workspace layout ----
  size_t off = 0;
  char* wsp = (char*)d_ws;
  auto alloc = [&](size_t n) { void* p = wsp + off; off += (n + 255) & ~(size_t)255; return p; };
  bf16*  Wqa_t  = (bf16*) alloc((size_t)QR * HD * 2);      // contiguous with
  bf16*  Wkva_t = (bf16*) alloc((size_t)640 * HD * 2);     //  ... Wqa_t (concat Bt)
  bf16*  Wqb_t  = (bf16*) alloc((size_t)NQB * QR * 2);
  bf16*  Wkvb_t = (bf16*) alloc((size_t)NKVB * KVR * 2);
  bf16*  Wo_t   = (bf16*) alloc((size_t)HD * HD * 2);
  bf16*  x_bf   = (bf16*) alloc((size_t)NTOK * HD * 2);
  bf16*  q_bhsd = (bf16*) alloc((size_t)B_ * NH * S_ * DQK * 2);
  bf16*  k_bhsd = (bf16*) alloc((size_t)B_ * NH * S_ * DQK * 2);
  bf16*  v_t    = (bf16*) alloc((size_t)B_ * NH * DV * S_ * 2);
  bf16*  att    = (bf16*) alloc((size_t)NTOK * 2048 * 2);
  char*  T      = (char*) alloc((size_t)33554432);         // 32 MB transient
  bf16*  xa  = (bf16*)T;                        // [NTOK][2176] = 17.8 MB
  bf16*  q_n = (bf16*)(T + 18874368);           // [NTOK][1536] = 12.6 MB
  bf16*  kv_l = (bf16*)(T + 18874368 + 12582912); // [NTOK][512] = 4.2 MB
  if (ws_size < off) return;

  cvt_bf16<<<(NTOK * HD / 4 + 255) / 256, 256, 0, stream>>>(x, x_bf, (long)NTOK * HD);
  TransArgs ta = {Wqa, Wkva, Wqb, Wkvb, Wo, Wqa_t, Wkva_t, Wqb_t, Wkvb_t, Wo_t};
  transpose_all<<<15104, 256, 0, stream>>>(ta);
  // ---- combined first-stage GEMM: xa = x_bf @ [Wqa | Wkva] ----
  gemm_bf16<bf16><<<dim3(NQKVA / 128, NTOK / 128), 256, 0, stream>>>(x_bf, Wqa_t, xa, NTOK, NQKVA, HD);
  // ---- merged norms + rope prep ----
  norm_prep<<<NTOK, 256, 0, stream>>>(xa, g_qa, g_kva, pos, cosT, sinT, q_n, kv_l, k_bhsd);
  // ---- Q path ----
  gemm_qf<<<dim3(NQB / 128, NTOK / 128), 256, 0, stream>>>(q_n, Wqb_t, pos, cosT, sinT, q_bhsd);
  // ---- KV path (v written transposed directly; v_trans eliminated) ----
  gemm_kvb<<<dim3(NKVB / 128, NTOK / 128), 256, 0, stream>>>(kv_l, Wkvb_t, k_bhsd, v_t);
  // ---- attention + output projection ----
  flash4<<<512, 512, 0, stream>>>(q_bhsd, k_bhsd, v_t, att);
  gemm_bf16<float><<<dim3(HD / 128, NTOK / 128), 256, 0, stream>>>(att, Wo_t, out, NTOK, HD, HD);
}

// Round 12
// 298.081 us; speedup vs baseline: 1.1562x; 1.0739x over previous
//
#include <hip/hip_runtime.h>
#include <hip/hip_bf16.h>

typedef __bf16 bf16;
typedef __bf16 bf16x8 __attribute__((ext_vector_type(8)));
typedef __bf16 bf16x4 __attribute__((ext_vector_type(4)));
typedef float f32x4 __attribute__((ext_vector_type(4)));

#define B_    2
#define S_    2048
#define HD    2048
#define NH    16
#define DQK   192
#define DV    128
#define QR    1536
#define KVR   512
#define NTOK  4096
#define NKVB  4096   /* N_HEADS*(D_NOPE+D_V) */
#define NQB   3072   /* N_HEADS*D_QK */
#define NQKVA 2176   /* QR + 640 (padded kv_a) */

#define EXP2F(x) __builtin_amdgcn_exp2f(x)

static __device__ __forceinline__ void gload16(const void* g, void* l) {
  __builtin_amdgcn_global_load_lds(
      (const __attribute__((address_space(1))) void*)g,
      (__attribute__((address_space(3))) void*)l, 16, 0, 0);
}

// ---------------- f32 -> bf16 convert ----------------
__global__ __launch_bounds__(256) void cvt_bf16(const float* __restrict__ in,
                                                bf16* __restrict__ out, long n) {
  long i = ((long)blockIdx.x * 256 + threadIdx.x) * 4;
  if (i + 3 < n) {
    float4 v = *(const float4*)(in + i);
    bf16x4 o = {(bf16)v.x, (bf16)v.y, (bf16)v.z, (bf16)v.w};
    *(bf16x4*)(out + i) = o;
  }
}

// ---------------- merged weight transposes: 5 segments, one launch ------------
struct TransArgs {
  const float *s0, *s1, *s2, *s3, *s4;
  bf16 *d0, *d1, *d2, *d3, *d4;
};
__global__ __launch_bounds__(256) void transpose_all(TransArgs a) {
  __shared__ float tile[32][33];
  int bid = blockIdx.x;
  int seg, rel;
  if      (bid < 3072)  { seg = 0; rel = bid; }
  else if (bid < 4352)  { seg = 1; rel = bid - 3072; }
  else if (bid < 8960)  { seg = 2; rel = bid - 4352; }
  else if (bid < 11008) { seg = 3; rel = bid - 8960; }
  else                  { seg = 4; rel = bid - 11008; }
  const float* in = seg == 0 ? a.s0 : seg == 1 ? a.s1 : seg == 2 ? a.s2 : seg == 3 ? a.s3 : a.s4;
  bf16* out       = seg == 0 ? a.d0 : seg == 1 ? a.d1 : seg == 2 ? a.d2 : seg == 3 ? a.d3 : a.d4;
  int R   = seg == 0 ? 2048 : seg == 1 ? 2048 : seg == 2 ? 1536 : seg == 3 ? 512 : 2048;
  int C   = seg == 0 ? 1536 : seg == 1 ? 576  : seg == 2 ? 3072 : seg == 3 ? 4096 : 2048;
  int Np  = seg == 0 ? 1536 : seg == 1 ? 640  : seg == 2 ? 3072 : seg == 3 ? 4096 : 2048;
  int nbx = seg == 0 ? 48   : seg == 1 ? 20   : seg == 2 ? 96   : seg == 3 ? 128 : 64;
  int c0 = (rel % nbx) * 32;
  int r0 = (rel / nbx) * 32;
  int tx = threadIdx.x & 31, ty = threadIdx.x >> 5;
#pragma unroll
  for (int i = 0; i < 4; ++i) {
    int r = r0 + ty + i * 8, c = c0 + tx;
    tile[ty + i * 8][tx] = (c < C) ? in[(long)r * C + c] : 0.f;
  }
  __syncthreads();
#pragma unroll
  for (int i = 0; i < 4; ++i) {
    int oc = c0 + ty + i * 8;
    if (oc < Np) out[(long)oc * R + r0 + tx] = (bf16)tile[tx][ty + i * 8];
  }
}

// ============ shared GEMM core: 128x128 tile, BK=64, XOR chunk swizzle ========
#define GEMM_CORE(A, Bt, K)                                                    \
  __shared__ bf16 As[128 * 64];                                                \
  __shared__ bf16 Bs[128 * 64];                                                \
  const int t = threadIdx.x;                                                   \
  const int l = t & 63;                                                        \
  const int w = t >> 6;                                                        \
  const int m0 = blockIdx.y * 128;                                             \
  const int n0 = blockIdx.x * 128;                                             \
  const int wr = (w >> 1) * 64;                                                \
  const int wc = (w & 1) * 64;                                                 \
  const int lr = l & 15;                                                       \
  const int lg = l >> 4;                                                       \
  f32x4 acc[4][4] = {};                                                        \
  for (int k0 = 0; k0 < (K); k0 += 64) {                                       \
    __syncthreads();                                                           \
    _Pragma("unroll")                                                          \
    for (int j = 0; j < 4; ++j) {                                              \
      int s = j * 256 + t;                                                     \
      int row = s >> 3, sc = s & 7;                                            \
      int c = sc ^ (row & 7);                                                  \
      gload16((A) + (long)(m0 + row) * (K) + k0 + c * 8,                       \
              As + (j * 256 + w * 64) * 8);                                    \
      gload16((Bt) + (long)(n0 + row) * (K) + k0 + c * 8,                      \
              Bs + (j * 256 + w * 64) * 8);                                    \
    }                                                                          \
    __syncthreads();                                                           \
    _Pragma("unroll")                                                          \
    for (int kh = 0; kh < 2; ++kh) {                                           \
      bf16x8 af[4], bfr[4];                                                    \
      _Pragma("unroll")                                                        \
      for (int m = 0; m < 4; ++m) {                                            \
        int row = wr + m * 16 + lr;                                            \
        af[m] = *(const bf16x8*)(As + row * 64 + (((kh * 4 + lg) ^ (row & 7)) << 3)); \
      }                                                                        \
      _Pragma("unroll")                                                        \
      for (int n = 0; n < 4; ++n) {                                            \
        int row = wc + n * 16 + lr;                                            \
        bfr[n] = *(const bf16x8*)(Bs + row * 64 + (((kh * 4 + lg) ^ (row & 7)) << 3)); \
      }                                                                        \
      _Pragma("unroll")                                                        \
      for (int m = 0; m < 4; ++m)                                              \
        _Pragma("unroll")                                                      \
        for (int n = 0; n < 4; ++n)                                            \
          acc[m][n] = __builtin_amdgcn_mfma_f32_16x16x32_bf16(af[m], bfr[n], acc[m][n], 0, 0, 0); \
    }                                                                          \
  }

// ---------------- generic GEMM: C[M][N] = A @ Bt^T ----------------------------
template <typename CT>
__global__ __launch_bounds__(256) void gemm_bf16(const bf16* __restrict__ A,
                                                 const bf16* __restrict__ Bt,
                                                 CT* __restrict__ C,
                                                 int M, int N, int K) {
  GEMM_CORE(A, Bt, K)
#pragma unroll
  for (int m = 0; m < 4; ++m)
#pragma unroll
    for (int n = 0; n < 4; ++n)
#pragma unroll
      for (int v = 0; v < 4; ++v) {
        int row = m0 + wr + m * 16 + lg * 4 + v;
        int col = n0 + wc + n * 16 + lr;
        C[(long)row * N + col] = (CT)acc[m][n][v];
      }
}

// ============ gemm8p core: 256x256 tile, BK=64, 8 waves, 2-dbuf, counted vmcnt
// Template-faithful properties (m201): 128 KB LDS (2 dbuf), vmcnt(8) at tile
// entry (never 0 mid-loop), 2-tile lookahead staged between MFMA clusters,
// 2 barriers/tile with NO drain, 64 MFMA/wave per barrier pair, setprio.
// Wave grid 2M x 4N; per-wave output 128x64 rows=wm*128.. cols=wn*64..
#define G8P_CORE(A, Bt, K)                                                     \
  __shared__ bf16 As_[2][256 * 64];                                            \
  __shared__ bf16 Bs_[2][256 * 64];                                            \
  const int t = threadIdx.x;                                                   \
  const int w = t >> 6, l = t & 63;                                            \
  const int lr = l & 15, lg = l >> 4;                                          \
  const int wm = w >> 2, wn = w & 3;                                           \
  const int m0 = blockIdx.y * 256, n0 = blockIdx.x * 256;                      \
  const int NT = (K) >> 6;                                                     \
  const int tr = t >> 3, sc = t & 7;                                           \
  f32x4 acc[8][4] = {};                                                        \
  auto stg = [&](int kt, int j) {                                              \
    int jj = j & 3;                                                            \
    int row = jj * 64 + tr;                                                    \
    int c = sc ^ (row & 7);                                                    \
    const bf16* src = (j < 4)                                                  \
        ? (A)  + (long)(m0 + row) * (K) + kt * 64 + c * 8                      \
        : (Bt) + (long)(n0 + row) * (K) + kt * 64 + c * 8;                     \
    bf16* dst = ((j < 4) ? As_[kt & 1] : Bs_[kt & 1]) + (jj * 512 + w * 64) * 8; \
    gload16(src, dst);                                                         \
  };                                                                           \
  _Pragma("unroll") for (int j = 0; j < 8; ++j) stg(0, j);                     \
  _Pragma("unroll") for (int j = 0; j < 8; ++j) stg(1, j);                     \
  for (int kt = 0; kt < NT; ++kt) {                                            \
    const bf16* Ab = As_[kt & 1];                                              \
    const bf16* Bb = Bs_[kt & 1];                                              \
    if (kt == NT - 1) { asm volatile("s_waitcnt vmcnt(0)" ::: "memory"); }     \
    else              { asm volatile("s_waitcnt vmcnt(8)" ::: "memory"); }     \
    __builtin_amdgcn_s_barrier();                                              \
    asm volatile("" ::: "memory");                                             \
    bf16x8 af[8][2], bfr[4][2];                                                \
    _Pragma("unroll")                                                          \
    for (int mi = 0; mi < 8; ++mi) {                                           \
      int row = wm * 128 + mi * 16 + lr;                                       \
      _Pragma("unroll")                                                        \
      for (int kh = 0; kh < 2; ++kh)                                           \
        af[mi][kh] = *(const bf16x8*)(Ab + row * 64 + (((kh * 4 + lg) ^ (row & 7)) << 3)); \
    }                                                                          \
    _Pragma("unroll")                                                          \
    for (int ni = 0; ni < 4; ++ni) {                                           \
      int row = wn * 64 + ni * 16 + lr;                                        \
      _Pragma("unroll")                                                        \
      for (int kh = 0; kh < 2; ++kh)                                           \
        bfr[ni][kh] = *(const bf16x8*)(Bb + row * 64 + (((kh * 4 + lg) ^ (row & 7)) << 3)); \
    }                                                                          \
    asm volatile("s_waitcnt lgkmcnt(0)" ::: "memory");                         \
    __builtin_amdgcn_sched_barrier(0);                                         \
    __builtin_amdgcn_s_setprio(1);                                             \
    _Pragma("unroll")                                                          \
    for (int mi = 0; mi < 8; ++mi)                                             \
      _Pragma("unroll")                                                        \
      for (int kh = 0; kh < 2; ++kh)                                           \
        acc[mi][0] = __builtin_amdgcn_mfma_f32_16x16x32_bf16(af[mi][kh], bfr[0][kh], acc[mi][0], 0, 0, 0); \
    __builtin_amdgcn_s_setprio(0);                                             \
    __builtin_amdgcn_s_barrier();  /* all waves' ds_reads done: dbufs free */  \
    asm volatile("" ::: "memory");                                             \
    bool more = (kt + 2) < NT;                                                 \
    if (more) { stg(kt + 2, 0); stg(kt + 2, 1); stg(kt + 2, 2); }              \
    __builtin_amdgcn_s_setprio(1);                                             \
    _Pragma("unroll")                                                          \
    for (int mi = 0; mi < 8; ++mi)                                             \
      _Pragma("unroll")                                                        \
      for (int kh = 0; kh < 2; ++kh)                                           \
        acc[mi][1] = __builtin_amdgcn_mfma_f32_16x16x32_bf16(af[mi][kh], bfr[1][kh], acc[mi][1], 0, 0, 0); \
    __builtin_amdgcn_s_setprio(0);                                             \
    if (more) { stg(kt + 2, 3); stg(kt + 2, 4); stg(kt + 2, 5); }              \
    __builtin_amdgcn_s_setprio(1);                                             \
    _Pragma("unroll")                                                          \
    for (int mi = 0; mi < 8; ++mi)                                             \
      _Pragma("unroll")                                                        \
      for (int kh = 0; kh < 2; ++kh)                                           \
        acc[mi][2] = __builtin_amdgcn_mfma_f32_16x16x32_bf16(af[mi][kh], bfr[2][kh], acc[mi][2], 0, 0, 0); \
    __builtin_amdgcn_s_setprio(0);                                             \
    if (more) { stg(kt + 2, 6); stg(kt + 2, 7); }                              \
    __builtin_amdgcn_s_setprio(1);                                             \
    _Pragma("unroll")                                                          \
    for (int mi = 0; mi < 8; ++mi)                                             \
      _Pragma("unroll")                                                        \
      for (int kh = 0; kh < 2; ++kh)                                           \
        acc[mi][3] = __builtin_amdgcn_mfma_f32_16x16x32_bf16(af[mi][kh], bfr[3][kh], acc[mi][3], 0, 0, 0); \
    __builtin_amdgcn_s_setprio(0);                                             \
  }

// ---------------- gemm8p fused q_f: RoPE + SCALE*LOG2E -> q_bhsd --------------
__global__ __launch_bounds__(512) void gemm8p_qf(const bf16* __restrict__ A,
                                                 const bf16* __restrict__ Bt,
                                                 const int* __restrict__ pos,
                                                 const float* __restrict__ cosT,
                                                 const float* __restrict__ sinT,
                                                 bf16* __restrict__ q_bhsd) {
  const float SCALE = 0.07216878364870323f * 1.4426950408889634f;
  G8P_CORE(A, Bt, QR)
  int c0 = n0 + wn * 64;
  int h = c0 / 192;
  int part = c0 - h * 192;            // 0, 64, or 128 (wave-uniform)
#pragma unroll
  for (int mi = 0; mi < 8; ++mi)
#pragma unroll
    for (int v = 0; v < 4; ++v) {
      int row = m0 + wm * 128 + mi * 16 + lg * 4 + v;
      int b = row >> 11, s = row & (S_ - 1);
      long base = ((long)(b * NH + h) * S_ + s) * DQK;
      if (part < 128) {
#pragma unroll
        for (int ni = 0; ni < 4; ++ni)
          q_bhsd[base + part + ni * 16 + lr] = (bf16)(acc[mi][ni][v] * SCALE);
      } else {
        int p = pos[s] & (S_ - 1);
        float c_lo = cosT[p * 32 + lr],      s_lo = sinT[p * 32 + lr];
        float c_hi = cosT[p * 32 + 16 + lr], s_hi = sinT[p * 32 + 16 + lr];
        float o0 = acc[mi][0][v] * c_lo - acc[mi][2][v] * s_lo;
        float o1 = acc[mi][1][v] * c_hi - acc[mi][3][v] * s_hi;
        float o2 = acc[mi][0][v] * s_lo + acc[mi][2][v] * c_lo;
        float o3 = acc[mi][1][v] * s_hi + acc[mi][3][v] * c_hi;
        q_bhsd[base + 128 + lr] = (bf16)(o0 * SCALE);
        q_bhsd[base + 144 + lr] = (bf16)(o1 * SCALE);
        q_bhsd[base + 160 + lr] = (bf16)(o2 * SCALE);
        q_bhsd[base + 176 + lr] = (bf16)(o3 * SCALE);
      }
    }
}

// ---------------- gemm8p fused kv_b: k -> k_bhsd, v -> v_t (direct transpose) -
__global__ __launch_bounds__(512) void gemm8p_kvb(const bf16* __restrict__ A,
                                                  const bf16* __restrict__ Bt,
                                                  bf16* __restrict__ k_bhsd,
                                                  bf16* __restrict__ v_t) {
  G8P_CORE(A, Bt, KVR)
  int c0 = n0 + wn * 64;
  int h = c0 >> 8;
  int dbase = c0 & 64;
  bool vpart = (c0 >> 7) & 1;
  if (!vpart) {
#pragma unroll
    for (int mi = 0; mi < 8; ++mi)
#pragma unroll
      for (int v = 0; v < 4; ++v) {
        int row = m0 + wm * 128 + mi * 16 + lg * 4 + v;
        int b = row >> 11, s = row & (S_ - 1);
        long base = ((long)(b * NH + h) * S_ + s) * DQK + dbase;
#pragma unroll
        for (int ni = 0; ni < 4; ++ni)
          k_bhsd[base + ni * 16 + lr] = (bf16)acc[mi][ni][v];
      }
  } else {
#pragma unroll
    for (int mi = 0; mi < 8; ++mi) {
      int row0 = m0 + wm * 128 + mi * 16 + lg * 4;
      int b = row0 >> 11, s = row0 & (S_ - 1);
#pragma unroll
      for (int ni = 0; ni < 4; ++ni) {
        int d = dbase + ni * 16 + lr;
        bf16x4 o = {(bf16)acc[mi][ni][0], (bf16)acc[mi][ni][1],
                    (bf16)acc[mi][ni][2], (bf16)acc[mi][ni][3]};
        *(bf16x4*)(v_t + ((long)(b * NH + h) * DV + d) * S_ + s) = o;
      }
    }
  }
}

// ---------------- merged norm+prep: waves 0-2 q-RMSNorm, wave 3 kv+rope -------
__global__ __launch_bounds__(256) void norm_prep(const bf16* __restrict__ xa,   // [NTOK][2176]
                                                 const float* __restrict__ g_qa,
                                                 const float* __restrict__ g_kva,
                                                 const int* __restrict__ pos,
                                                 const float* __restrict__ cosT,
                                                 const float* __restrict__ sinT,
                                                 bf16* __restrict__ q_n,       // [NTOK][1536]
                                                 bf16* __restrict__ kv_l,      // [NTOK][512]
                                                 bf16* __restrict__ k_bhsd) {  // [B][H][S][192]
  int row = blockIdx.x;
  int t = threadIdx.x;
  int b = row >> 11, s = row & (S_ - 1);
  const bf16* xr = xa + (long)row * NQKVA;
  __shared__ float red[3];
  __shared__ bf16 rope_s[64];
  float vf[8];
  if (t < 192) {
    bf16x8 vv = *(const bf16x8*)(xr + t * 8);
    float ss = 0.f;
#pragma unroll
    for (int e = 0; e < 8; ++e) { vf[e] = (float)vv[e]; ss += vf[e] * vf[e]; }
#pragma unroll
    for (int m = 1; m < 64; m <<= 1) ss += __shfl_xor(ss, m);
    if ((t & 63) == 0) red[t >> 6] = ss;
  } else {
    int tt = t - 192;
    const bf16* xl = xr + QR;
    bf16x8 vv = *(const bf16x8*)(xl + tt * 8);
    float ss = 0.f;
#pragma unroll
    for (int e = 0; e < 8; ++e) { vf[e] = (float)vv[e]; ss += vf[e] * vf[e]; }
#pragma unroll
    for (int m = 1; m < 64; m <<= 1) ss += __shfl_xor(ss, m);
    float rs = rsqrtf(ss / KVR + 1e-5f);
    bf16x8 o;
#pragma unroll
    for (int e = 0; e < 8; ++e) o[e] = (bf16)(vf[e] * rs * g_kva[tt * 8 + e]);
    *(bf16x8*)(kv_l + (long)row * KVR + tt * 8) = o;
    if (tt < 32) {
      int p = pos[s] & (S_ - 1);
      float c = cosT[p * 32 + tt], sn = sinT[p * 32 + tt];
      float x0 = (float)xl[512 + tt], x1 = (float)xl[544 + tt];
      rope_s[tt] = (bf16)(x0 * c - x1 * sn);
      rope_s[32 + tt] = (bf16)(x0 * sn + x1 * c);
    }
  }
  __syncthreads();
  if (t < 192) {
    float ss = red[0] + red[1] + red[2];
    float rs = rsqrtf(ss / QR + 1e-5f);
    bf16x8 o;
#pragma unroll
    for (int e = 0; e < 8; ++e) o[e] = (bf16)(vf[e] * rs * g_qa[t * 8 + e]);
    *(bf16x8*)(q_n + (long)row * QR + t * 8) = o;
  } else {
    int tt = t - 192;
    bf16x8 rv = *(const bf16x8*)&rope_s[(tt & 7) * 8];
    long base0 = ((long)(b * NH + (tt >> 3)) * S_ + s) * DQK + 128 + (tt & 7) * 8;
    long base1 = ((long)(b * NH + 8 + (tt >> 3)) * S_ + s) * DQK + 128 + (tt & 7) * 8;
    *(bf16x8*)(k_bhsd + base0) = rv;
    *(bf16x8*)(k_bhsd + base1) = rv;
  }
}

// ---------------- flash v4: 8 waves x 16 q-rows (QBLK=128), shared K/V tiles --
#define KVB  64
#define DVP  144
__global__ __launch_bounds__(512) void flash4(const bf16* __restrict__ q_bhsd,
                                              const bf16* __restrict__ k_bhsd,
                                              const bf16* __restrict__ v_t,
                                              bf16* __restrict__ att) {  // [NTOK][2048]
  __shared__ bf16 Ks[KVB * DQK];      // 24 KB, swizzled 16B chunks
  __shared__ bf16 Vs[DVP * KVB];      // 18 KB, rows 0-127 staged, 128-143 const
  __shared__ bf16 Ps[8][16 * 72];     // 18 KB, per-wave P, padded to 72
  int bid = blockIdx.x;
  int bh = bid & 31;                  // head-of-batch: fixes XCD = bh%8
  int qt = 15 - (bid >> 5);           // heaviest (most k-tiles) first
  int b = bh >> 4, h = bh & 15;
  int q0 = qt * 128;
  int t = threadIdx.x;
  int w = t >> 6, l = t & 63;
  int lr = l & 15, lg = l >> 4;
  int qw = q0 + w * 16;               // this wave's first q row

  const bf16* Qb = q_bhsd + (long)bh * S_ * DQK;
  const bf16* Kb = k_bhsd + (long)bh * S_ * DQK;
  const bf16* Vb = v_t + (long)bh * DV * S_;

  // init ones/zero rows of Vs (persist across tiles; staging never touches them)
  if (t < 128) {
    int rr = 128 + (t >> 3), cc = (t & 7) * 8;
    bf16 val = (bf16)((rr == 128) ? 1.0f : 0.0f);
    bf16x8 vvv = {val, val, val, val, val, val, val, val};
    *(bf16x8*)(Vs + rr * KVB + cc) = vvv;
  }

  bf16x8 qf[6];
#pragma unroll
  for (int t6 = 0; t6 < 6; ++t6)
    qf[t6] = *(const bf16x8*)(Qb + (long)(qw + lr) * DQK + t6 * 32 + lg * 8);

  f32x4 oacc[9] = {};                 // [0..7] output, [8] = l (ones-row)
  float mrow[4] = {-1e30f, -1e30f, -1e30f, -1e30f};
  const int lr7 = lr & 7;

  int nkt = 2 * qt + 2;
  for (int kt = 0; kt < nkt; ++kt) {
    int k0 = kt * KVB;
    __syncthreads();
    // stage K: 1536 chunks (3 x 512); slot s holds global chunk (r, c^(r&7))
#pragma unroll
    for (int j = 0; j < 3; ++j) {
      int s = j * 512 + t;
      int r = s / 24, c1 = s - r * 24;
      int c = c1 ^ (r & 7);
      gload16(Kb + (long)(k0 + r) * DQK + c * 8, Ks + (j * 512 + w * 64) * 8);
    }
    // stage V: 1024 chunks (2 x 512), rows 0..127 only
#pragma unroll
    for (int j = 0; j < 2; ++j) {
      int s = j * 512 + t;
      int d = s >> 3, c1 = s & 7;
      int c = c1 ^ (d & 7);
      gload16(Vb + (long)d * S_ + k0 + c * 8, Vs + (j * 512 + w * 64) * 8);
    }
    __syncthreads();
    if (k0 > qw + 15) continue;       // fully masked for this wave

    // ---- QK^T: sacc[n] = scores[q=lg*4+v][k=n*16+lr] (log2-domain) ----
    f32x4 sacc[4] = {};
#pragma unroll
    for (int n = 0; n < 4; ++n) {
      int rk = n * 16 + lr;
#pragma unroll
      for (int t6 = 0; t6 < 6; ++t6) {
        bf16x8 kf = *(const bf16x8*)(Ks + rk * DQK + (((t6 * 4 + lg) ^ lr7) << 3));
        sacc[n] = __builtin_amdgcn_mfma_f32_16x16x32_bf16(qf[t6], kf, sacc[n], 0, 0, 0);
      }
    }
    // ---- causal mask (diagonal tiles only) ----
    if (k0 + KVB - 1 > qw) {
#pragma unroll
      for (int n = 0; n < 4; ++n)
#pragma unroll
        for (int v = 0; v < 4; ++v) {
          int r = lg * 4 + v, c = n * 16 + lr;
          if (k0 + c > qw + r) sacc[n][v] = -1e30f;
        }
    }
    // ---- tile row-max ----
    float mv[4];
#pragma unroll
    for (int v = 0; v < 4; ++v) {
      mv[v] = fmaxf(fmaxf(sacc[0][v], sacc[1][v]), fmaxf(sacc[2][v], sacc[3][v]));
#pragma unroll
      for (int msk = 1; msk < 16; msk <<= 1) mv[v] = fmaxf(mv[v], __shfl_xor(mv[v], msk));
    }
    // ---- defer-max: rescale only if some row max grew by > 8 (log2) ----
    bool grow = (mv[0] > mrow[0] + 8.f) | (mv[1] > mrow[1] + 8.f) |
                (mv[2] > mrow[2] + 8.f) | (mv[3] > mrow[3] + 8.f);
    if (__any(grow)) {
      float corr[4];
#pragma unroll
      for (int v = 0; v < 4; ++v) {
        float mt = fmaxf(mrow[v], mv[v]);
        corr[v] = EXP2F(mrow[v] - mt);
        mrow[v] = mt;
      }
#pragma unroll
      for (int dn = 0; dn < 9; ++dn)
#pragma unroll
        for (int v = 0; v < 4; ++v) oacc[dn][v] *= corr[v];
    }
    // ---- P = exp2(s - mrow); P -> LDS (per-wave, padded) ----
#pragma unroll
    for (int v = 0; v < 4; ++v)
#pragma unroll
      for (int n = 0; n < 4; ++n)
        Ps[w][(lg * 4 + v) * 72 + n * 16 + lr] = (bf16)EXP2F(sacc[n][v] - mrow[v]);
    // ---- PV: oacc[dn] += P[16x64] @ V^T; dn=8 hits the ones-row => l ----
#pragma unroll
    for (int kc = 0; kc < 2; ++kc) {
      bf16x8 pf = *(const bf16x8*)(Ps[w] + lr * 72 + kc * 32 + lg * 8);
#pragma unroll
      for (int dn = 0; dn < 9; ++dn) {
        int d = dn * 16 + lr;
        bf16x8 vf = *(const bf16x8*)(Vs + d * KVB + (((kc * 4 + lg) ^ lr7) << 3));
        oacc[dn] = __builtin_amdgcn_mfma_f32_16x16x32_bf16(pf, vf, oacc[dn], 0, 0, 0);
      }
    }
  }
  // ---- epilogue: l lives in column d=128 (lanes lr==0); broadcast + divide ----
  float rl[4];
#pragma unroll
  for (int v = 0; v < 4; ++v) {
    float lv = __shfl(oacc[8][v], lg * 16);
    rl[v] = 1.0f / lv;
  }
#pragma unroll
  for (int dn = 0; dn < 8; ++dn)
#pragma unroll
    for (int v = 0; v < 4; ++v) {
      int r = lg * 4 + v;
      float o = oacc[dn][v] * rl[v];
      att[((long)(b * S_ + qw + r)) * 2048 + h * 128 + dn * 16 + lr] = (bf16)o;
    }
}

extern "C" void kernel_launch(void* const* d_in, const int* in_sizes, int n_in,
                              void* d_out, int out_size, void* d_ws, size_t ws_size,
                              hipStream_t stream) {
  const float* x        = (const float*)d_in[0];
  const int* pos        = (const int*)d_in[1];   // harness passes integers as int32
  const float* Wqa      = (const float*)d_in[2];
  const float* g_qa     = (const float*)d_in[3];
  const float* Wqb      = (const float*)d_in[4];
  const float* Wkva     = (const float*)d_in[5];
  const float* g_kva    = (const float*)d_in[6];
  const float* Wkvb     = (const float*)d_in[7];
  const float* Wo       = (const float*)d_in[8];
  const float* cosT     = (const float*)d_in[9];
  const float* sinT     = (const float*)d_in[10];
  float* out            = (float*)d_out;

  // ---- workspace layout ----
  size_t off = 0;
  char* wsp = (char*)d_ws;
  auto alloc = [&](size_t n) { void* p = wsp + off; off += (n + 255) & ~(size_t)255; return p; };
  bf16*  Wqa_t  = (bf16*) alloc((size_t)QR * HD * 2);      // contiguous with
  bf16*  Wkva_t = (bf16*) alloc((size_t)640 * HD * 2);     //  ... Wqa_t (concat Bt)
  bf16*  Wqb_t  = (bf16*) alloc((size_t)NQB * QR * 2);
  bf16*  Wkvb_t = (bf16*) alloc((size_t)NKVB * KVR * 2);
  bf16*  Wo_t   = (bf16*) alloc((size_t)HD * HD * 2);
  bf16*  x_bf   = (bf16*) alloc((size_t)NTOK * HD * 2);
  bf16*  q_bhsd = (bf16*) alloc((size_t)B_ * NH * S_ * DQK * 2);
  bf16*  k_bhsd = (bf16*) alloc((size_t)B_ * NH * S_ * DQK * 2);
  bf16*  v_t    = (bf16*) alloc((size_t)B_ * NH * DV * S_ * 2);
  bf16*  att    = (bf16*) alloc((size_t)NTOK * 2048 * 2);
  char*  T      = (char*) alloc((size_t)33554432);         // 32 MB transient
  bf16*  xa  = (bf16*)T;                        // [NTOK][2176] = 17.8 MB
  bf16*  q_n = (bf16*)(T + 18874368);           // [NTOK][1536] = 12.6 MB
  bf16*  kv_l = (bf16*)(T + 18874368 + 12582912); // [NTOK][512] = 4.2 MB
  if (ws_size < off) return;

  cvt_bf16<<<(NTOK * HD / 4 + 255) / 256, 256, 0, stream>>>(x, x_bf, (long)NTOK * HD);
  TransArgs ta = {Wqa, Wkva, Wqb, Wkvb, Wo, Wqa_t, Wkva_t, Wqb_t, Wkvb_t, Wo_t};
  transpose_all<<<15104, 256, 0, stream>>>(ta);
  // ---- combined first-stage GEMM: xa = x_bf @ [Wqa | Wkva] ----
  gemm_bf16<bf16><<<dim3(NQKVA / 128, NTOK / 128), 256, 0, stream>>>(x_bf, Wqa_t, xa, NTOK, NQKVA, HD);
  // ---- merged norms + rope prep ----
  norm_prep<<<NTOK, 256, 0, stream>>>(xa, g_qa, g_kva, pos, cosT, sinT, q_n, kv_l, k_bhsd);
  // ---- Q path (8-phase-style 256^2 core) ----
  gemm8p_qf<<<dim3(NQB / 256, NTOK / 256), 512, 0, stream>>>(q_n, Wqb_t, pos, cosT, sinT, q_bhsd);
  // ---- KV path (8-phase-style 256^2 core; v written transposed directly) ----
  gemm8p_kvb<<<dim3(NKVB / 256, NTOK / 256), 512, 0, stream>>>(kv_l, Wkvb_t, k_bhsd, v_t);
  // ---- attention + output projection ----
  flash4<<<512, 512, 0, stream>>>(q_bhsd, k_bhsd, v_t, att);
  gemm_bf16<float><<<dim3(HD / 128, NTOK / 128), 256, 0, stream>>>(att, Wo_t, out, NTOK, HD, HD);
}